// Round 4
// baseline (225.680 us; speedup 1.0000x reference)
//
#include <hip/hip_runtime.h>

#define BB 8
#define CC 512
#define LL 2048
#define GG 4
#define CPG 128   // channels per group

typedef _Float16 f16;
typedef _Float16 f16x8 __attribute__((ext_vector_type(8)));
typedef float f32x4 __attribute__((ext_vector_type(4)));

__device__ __forceinline__ void gload_lds16(const f16* g, f16* l)
{
    __builtin_amdgcn_global_load_lds(
        (__attribute__((address_space(1))) void*)g,
        (__attribute__((address_space(3))) void*)l, 16, 0, 0);
}

// swizzled read of one 16B fragment from a BK=32 tile (rows of 64B):
// phys = (row*64 + lhi*16) ^ ((row&3)<<4)   -> at most 2-way bank alias (free)
__device__ __forceinline__ f16x8 rd32(const char* tile, int row, int lhi)
{
    return *(const f16x8*)(tile + (((row << 6) + (lhi << 4)) ^ ((row & 3) << 4)));
}

// ---------------------------------------------------------------------------
// Phased GEMM, BK=32, 3-slot LDS rotation, counted vmcnt (never drains
// mid-loop), 2-deep prefetch.  C[M,N] = alpha*A[M,K]·B[N,K]^T (+bias)(+resid)
// 8 waves; per-wave cols always 64 (4 n-frags); per-wave rows = BM/NWR.
//   BM=BN=256: NWC=4, NWR=2, RPW=128, MF=8, 2 phases/tile   (GEMM1, GEMM3)
//   256x128 / 128x256: per-wave 64x64, MF=4, 1 phase/tile   (GEMM2,4,5)
// Staging: global_load_lds w=16, linear LDS dest, inverse-swizzled source:
//   dest byte = unit*8192 + tid*16 -> row = tid>>2, chunk c = tid&3,
//   src k-octet = c ^ (row&3).
// ---------------------------------------------------------------------------
template<int BM, int BN, int BIAS_MODE, bool RESID, typename OUT_T>
__global__ __launch_bounds__(512, 2) void gemm32(
    const f16* __restrict__ A, size_t sA,
    const f16* __restrict__ B, size_t sB,
    OUT_T* __restrict__ Co, size_t sC,
    const float* __restrict__ resid, size_t sR,
    const float* __restrict__ bias,
    int K, int lda, int ldb, int ldc, float alpha)
{
    constexpr int NWC = BN / 64;      // waves along N
    constexpr int NWR = 8 / NWC;      // waves along M
    constexpr int RPW = BM / NWR;     // rows per wave (128 or 64)
    constexpr int MF  = RPW / 16;     // m-frags per wave (8 or 4)
    constexpr int NPH = MF / 4;       // phases per tile (2 or 1)
    constexpr int AU  = BM / 128;     // A stage units (8KB each)
    constexpr int BU  = BN / 128;
    constexpr int LOADS = AU + BU;    // gload_lds per thread per tile

    const int tid = threadIdx.x, lane = tid & 63, w = tid >> 6;
    const int l15 = lane & 15, lhi = lane >> 4;
    const int wr = w / NWC, wc = w % NWC;
    const int bm = blockIdx.y, bn = blockIdx.x, bz = blockIdx.z;

    A  += (size_t)bz * sA + (size_t)(bm * BM) * lda;
    B  += (size_t)bz * sB + (size_t)(bn * BN) * ldb;
    Co += (size_t)bz * sC;

    __shared__ char sAbuf[3][BM * 64];
    __shared__ char sBbuf[3][BN * 64];

    f32x4 acc[MF][4] = {};

    const int srow = tid >> 2;                               // 0..127
    const int scol = ((tid & 3) ^ ((tid >> 2) & 3)) * 8;     // inverse-swizzle
    const int woff = w * 1024;                               // wave chunk in unit

    auto STAGE_A = [&](int t) {
        char* base = sAbuf[t % 3];
#pragma unroll
        for (int u = 0; u < AU; ++u)
            gload_lds16(A + (size_t)(u * 128 + srow) * lda + (t * 32 + scol),
                        (f16*)(base + u * 8192 + woff));
    };
    auto STAGE_B = [&](int t) {
        char* base = sBbuf[t % 3];
#pragma unroll
        for (int u = 0; u < BU; ++u)
            gload_lds16(B + (size_t)(u * 128 + srow) * ldb + (t * 32 + scol),
                        (f16*)(base + u * 8192 + woff));
    };

    // prologue: stage tiles 0 and 1; confirm tile 0 (keep tile 1 in flight)
    STAGE_A(0); STAGE_B(0);
    STAGE_A(1); STAGE_B(1);
    if constexpr (LOADS == 4) asm volatile("s_waitcnt vmcnt(4)" ::: "memory");
    else                      asm volatile("s_waitcnt vmcnt(3)" ::: "memory");
    __builtin_amdgcn_s_barrier();

    const int NT = K >> 5;
    for (int t = 0; t < NT; ++t) {
        const char* cA = sAbuf[t % 3];
        const char* cB = sBbuf[t % 3];
        const int mode = (t < NT - 2) ? 2 : ((t == NT - 2) ? 1 : 0);
        f16x8 b[4];
#pragma unroll
        for (int ph = 0; ph < NPH; ++ph) {
            f16x8 a[4];
#pragma unroll
            for (int i = 0; i < 4; ++i)
                a[i] = rd32(cA, wr * RPW + (ph * 4 + i) * 16 + l15, lhi);
            if (ph == 0) {
#pragma unroll
                for (int n = 0; n < 4; ++n)
                    b[n] = rd32(cB, wc * 64 + n * 16 + l15, lhi);
            }
            if (mode == 2) {
                if (NPH == 1)      { STAGE_A(t + 2); STAGE_B(t + 2); }
                else if (ph == 0)  STAGE_A(t + 2);
                else               STAGE_B(t + 2);
            }
            if (ph == NPH - 1) {
                if (mode == 2) {
                    if constexpr (LOADS == 4) asm volatile("s_waitcnt vmcnt(4)" ::: "memory");
                    else                      asm volatile("s_waitcnt vmcnt(3)" ::: "memory");
                } else if (mode == 1) {
                    asm volatile("s_waitcnt vmcnt(0)" ::: "memory");
                }
            }
            __builtin_amdgcn_s_barrier();
            asm volatile("s_waitcnt lgkmcnt(0)" ::: "memory");
            __builtin_amdgcn_s_setprio(1);
#pragma unroll
            for (int i = 0; i < 4; ++i)
#pragma unroll
                for (int n = 0; n < 4; ++n)
                    acc[ph * 4 + i][n] = __builtin_amdgcn_mfma_f32_16x16x32_f16(
                        a[i], b[n], acc[ph * 4 + i][n], 0, 0, 0);
            __builtin_amdgcn_s_setprio(0);
            __builtin_amdgcn_s_barrier();
        }
    }

    // epilogue
#pragma unroll
    for (int m = 0; m < MF; ++m) {
#pragma unroll
        for (int n = 0; n < 4; ++n) {
            int col = bn * BN + wc * 64 + n * 16 + l15;
#pragma unroll
            for (int r = 0; r < 4; ++r) {
                int row = bm * BM + wr * RPW + m * 16 + lhi * 4 + r;
                float v = acc[m][n][r] * alpha;
                if (BIAS_MODE == 1) v += bias[row];
                if (BIAS_MODE == 2) v += bias[col];
                if (RESID) v += resid[(size_t)bz * sR + (size_t)row * ldc + col];
                Co[(size_t)row * ldc + col] = (OUT_T)v;
            }
        }
    }
}

// ---------------------------------------------------------------------------
// Weight conversion: fp32 -> f16, build [qw;kw] stack and [qb;kb] concat
// ---------------------------------------------------------------------------
__global__ __launch_bounds__(256) void convert_w(
    const float* __restrict__ qw, const float* __restrict__ kw,
    const float* __restrict__ vw, const float* __restrict__ pw,
    const float* __restrict__ qb, const float* __restrict__ kb,
    f16* __restrict__ Wqk, f16* __restrict__ Wv, f16* __restrict__ Wp,
    float* __restrict__ qkb)
{
    int i = blockIdx.x * 256 + threadIdx.x;
    if (i < CC * CC) {
        Wqk[i]           = (f16)qw[i];
        Wqk[CC * CC + i] = (f16)kw[i];
        Wv[i]            = (f16)vw[i];
        Wp[i]            = (f16)pw[i];
    }
    if (i < CC) { qkb[i] = qb[i]; qkb[CC + i] = kb[i]; }
}

// ---------------------------------------------------------------------------
// GroupNorm stage A: partial sums per (b, g, slice)
// ---------------------------------------------------------------------------
__global__ __launch_bounds__(256) void gn_partial(
    const float* __restrict__ x, float2* __restrict__ part)
{
    int s = blockIdx.x, g = blockIdx.y, b = blockIdx.z;
    const float4* p = (const float4*)(x + (size_t)b * CC * LL + (size_t)g * CPG * LL
                                        + (size_t)s * 8192);
    float sum = 0.f, sq = 0.f;
    for (int i = threadIdx.x; i < 2048; i += 256) {
        float4 v = p[i];
        sum += v.x + v.y + v.z + v.w;
        sq  += v.x * v.x + v.y * v.y + v.z * v.z + v.w * v.w;
    }
    for (int o = 32; o; o >>= 1) { sum += __shfl_xor(sum, o); sq += __shfl_xor(sq, o); }
    __shared__ float2 red[4];
    int wave = threadIdx.x >> 6, lane = threadIdx.x & 63;
    if (lane == 0) red[wave] = make_float2(sum, sq);
    __syncthreads();
    if (threadIdx.x == 0) {
        float S = red[0].x + red[1].x + red[2].x + red[3].x;
        float Q = red[0].y + red[1].y + red[2].y + red[3].y;
        part[((size_t)b * GG + g) * 32 + s] = make_float2(S, Q);
    }
}

__global__ void gn_finalize(const float2* __restrict__ part, float2* __restrict__ stats)
{
    int t = threadIdx.x;
    if (t < BB * GG) {
        float s = 0.f, q = 0.f;
        for (int i = 0; i < 32; ++i) { float2 p = part[t * 32 + i]; s += p.x; q += p.y; }
        const float invN = 1.0f / (float)(CPG * LL);
        float mean = s * invN;
        float var  = q * invN - mean * mean;
        stats[t] = make_float2(mean, rsqrtf(var + 1e-6f));
    }
}

// GroupNorm normalize + affine + TRANSPOSE: x [C,L] fp32 -> xnT [L,C] f16
__global__ __launch_bounds__(256) void gn_norm_t(
    const float* __restrict__ x, const float2* __restrict__ stats,
    const float* __restrict__ gw, const float* __restrict__ gb,
    f16* __restrict__ xnT)
{
    __shared__ float t[64][65];
    int l0 = blockIdx.x * 64, c0 = blockIdx.y * 64, b = blockIdx.z;
    float2 st = stats[b * GG + (c0 >> 7)];
    const float* xb = x + (size_t)b * CC * LL;
    for (int i = threadIdx.x; i < 4096; i += 256) {
        int c = i >> 6, l = i & 63;
        float v = xb[(size_t)(c0 + c) * LL + l0 + l];
        t[c][l] = (v - st.x) * st.y * gw[c0 + c] + gb[c0 + c];
    }
    __syncthreads();
    f16* o = xnT + (size_t)b * LL * CC;
    for (int i = threadIdx.x; i < 4096; i += 256) {
        int l = i >> 6, c = i & 63;
        o[(size_t)(l0 + l) * CC + c0 + c] = (f16)t[c][l];
    }
}

// ---------------------------------------------------------------------------
// Row softmax in-place on f16 P [L, L] per (b, row). grid (LL, BB), block 256.
// ---------------------------------------------------------------------------
__global__ __launch_bounds__(256) void softmax_rows(f16* __restrict__ P)
{
    int i = blockIdx.x, b = blockIdx.y;
    f16* row = P + ((size_t)b * LL + (size_t)i) * LL;
    int tid = threadIdx.x;
    f16x8 v = ((const f16x8*)row)[tid];
    float f[8], mx = -1e30f;
#pragma unroll
    for (int j = 0; j < 8; ++j) { f[j] = (float)v[j]; mx = fmaxf(mx, f[j]); }
    for (int o = 32; o; o >>= 1) mx = fmaxf(mx, __shfl_xor(mx, o));
    __shared__ float red1[4];
    __shared__ float red2[4];
    int wave = tid >> 6, lane = tid & 63;
    if (lane == 0) red1[wave] = mx;
    __syncthreads();
    mx = fmaxf(fmaxf(red1[0], red1[1]), fmaxf(red1[2], red1[3]));
    float s = 0.f;
#pragma unroll
    for (int j = 0; j < 8; ++j) { f[j] = __expf(f[j] - mx); s += f[j]; }
    for (int o = 32; o; o >>= 1) s += __shfl_xor(s, o);
    if (lane == 0) red2[wave] = s;
    __syncthreads();
    s = red2[0] + red2[1] + red2[2] + red2[3];
    float inv = 1.0f / s;
    f16x8 o8;
#pragma unroll
    for (int j = 0; j < 8; ++j) o8[j] = (f16)(f[j] * inv);
    ((f16x8*)row)[tid] = o8;
}

// Fallback marker if workspace is too small (distinct absmax signal ~12345)
__global__ void fill_marker(float* out, int n)
{
    int i = blockIdx.x * 256 + threadIdx.x;
    if (i < n) out[i] = 12345.0f;
}

// ---------------------------------------------------------------------------
extern "C" void kernel_launch(void* const* d_in, const int* in_sizes, int n_in,
                              void* d_out, int out_size, void* d_ws, size_t ws_size,
                              hipStream_t stream)
{
    const float* x  = (const float*)d_in[0];
    const float* gw = (const float*)d_in[1];
    const float* gb = (const float*)d_in[2];
    const float* qw = (const float*)d_in[3];
    const float* qb = (const float*)d_in[4];
    const float* kw = (const float*)d_in[5];
    const float* kb = (const float*)d_in[6];
    const float* vw = (const float*)d_in[7];
    const float* vb = (const float*)d_in[8];
    const float* pw = (const float*)d_in[9];
    const float* pb = (const float*)d_in[10];
    float* out = (float*)d_out;

    // workspace layout (bytes)
    char* w = (char*)d_ws;
    float2* part  = (float2*)w;                       //   8 KB
    float2* stats = (float2*)(w + 8192);              //   256 B
    f16* Wqk  = (f16*)(w + 16384);                    //   1 MB   [1024,512]
    f16* Wv   = Wqk + (size_t)1024 * CC;              // 512 KB   [512,512]
    f16* Wp   = Wv  + (size_t)CC * CC;                // 512 KB
    float* qkb = (float*)(Wp + (size_t)CC * CC);      //   4 KB
    f16* xnT  = (f16*)((char*)qkb + 4096);            // 16 MB    [B][L,C]
    f16* QK   = xnT + (size_t)BB * LL * CC;           // 32 MB    [B][L,1024]
    f16* Vm   = QK  + (size_t)BB * LL * 1024;         // 16 MB    [B][C,L]
    f16* Pm   = Vm  + (size_t)BB * CC * LL;           // 64 MB    [B][L,L]
    f16* O2   = xnT;  // alias: xnT dead after gemm2  //          [B][L,C]
    size_t need = (size_t)((char*)(Pm + (size_t)BB * LL * LL) - w);
    if (ws_size < need) {
        fill_marker<<<(out_size + 255) / 256, 256, 0, stream>>>(out, out_size);
        return;
    }

    convert_w<<<dim3((CC * CC + 255) / 256), 256, 0, stream>>>(
        qw, kw, vw, pw, qb, kb, Wqk, Wv, Wp, qkb);
    gn_partial<<<dim3(32, GG, BB), 256, 0, stream>>>(x, part);
    gn_finalize<<<1, 64, 0, stream>>>(part, stats);
    gn_norm_t<<<dim3(LL / 64, CC / 64, BB), 256, 0, stream>>>(x, stats, gw, gb, xnT);

    // GEMM1: [Q|K]t[l, n] = xnT[l,:] . Wqk[n,:] + qkb[n]     (M=L, N=1024, K=C)
    gemm32<256, 256, 2, false, f16><<<dim3(4, 8, BB), 512, 0, stream>>>(
        xnT, (size_t)LL * CC, Wqk, 0, QK, (size_t)LL * 1024, nullptr, 0, qkb,
        CC, CC, CC, 1024, 1.0f);

    // GEMM2: V[c, l] = Wv[c,:] . xnT[l,:] + vb[c]            (M=C, N=L, K=C)
    gemm32<128, 256, 1, false, f16><<<dim3(8, 4, BB), 512, 0, stream>>>(
        Wv, 0, xnT, (size_t)LL * CC, Vm, (size_t)CC * LL, nullptr, 0, vb,
        CC, CC, CC, LL, 1.0f);

    // GEMM3: S[i, j] = scale * Qt[i,:] . Kt[j,:]             (M=L, N=L, K=C)
    gemm32<256, 256, 0, false, f16><<<dim3(8, 8, BB), 512, 0, stream>>>(
        QK, (size_t)LL * 1024, QK + CC, (size_t)LL * 1024, Pm, (size_t)LL * LL,
        nullptr, 0, nullptr,
        CC, 1024, 1024, LL, 0.04419417382415922f);

    softmax_rows<<<dim3(LL, BB), 256, 0, stream>>>(Pm);

    // GEMM4: O2[i, c] = P[i,:] . V[c,:]                      (M=L, N=C, K=L)
    gemm32<256, 128, 0, false, f16><<<dim3(4, 8, BB), 512, 0, stream>>>(
        Pm, (size_t)LL * LL, Vm, (size_t)CC * LL, O2, (size_t)LL * CC,
        nullptr, 0, nullptr,
        LL, LL, LL, CC, 1.0f);

    // GEMM5: out[c, l] = Wp[c,:] . O2[l,:] + pb[c] + x[c,l]  (M=C, N=L, K=C)
    gemm32<128, 256, 1, true, float><<<dim3(8, 4, BB), 512, 0, stream>>>(
        Wp, 0, O2, (size_t)LL * CC, out, (size_t)CC * LL, x, (size_t)CC * LL, pb,
        CC, CC, CC, LL, 1.0f);
}

// Round 5
// 207.071 us; speedup vs baseline: 1.0899x; 1.0899x over previous
//
#include <hip/hip_runtime.h>

#define BB 8
#define CC 512
#define LL 2048
#define GG 4
#define CPG 128   // channels per group

typedef _Float16 f16;
typedef _Float16 f16x8 __attribute__((ext_vector_type(8)));
typedef float f32x4 __attribute__((ext_vector_type(4)));

__device__ __forceinline__ void gload_lds16(const f16* g, f16* l)
{
    __builtin_amdgcn_global_load_lds(
        (__attribute__((address_space(1))) void*)g,
        (__attribute__((address_space(3))) void*)l, 16, 0, 0);
}

// R2-verified zero-conflict swizzle. Tile rows are 64 f16 = 128B.
// phys = (row*128 + byteCol) ^ ((row&7)<<4)
__device__ __forceinline__ f16x8 rd_swz(const char* tile, int row, int byteCol)
{
    return *(const f16x8*)(tile + (((row << 7) + byteCol) ^ ((row & 7) << 4)));
}

// ---------------------------------------------------------------------------
// Phased GEMM (m201 geometry): C[M,N] = alpha*A[M,K]·B[N,K]^T (+bias)(+resid)
// BK=64, 8 waves as NWRxNWC, per-wave RPWxCPW (CPW always 64).
//   (256,256): 2Mx4N, per-wave 128x64, MF=8 -> 4 phases, DEPTH=2 (128KB LDS)
//   (256,128): 4Mx2N, per-wave  64x64, MF=4 -> 2 phases, DEPTH=3 (144KB LDS)
//   (128,256): 2Mx4N, per-wave  64x64, MF=4 -> 2 phases, DEPTH=3 (144KB LDS)
// Staging: global_load_lds w=16, linear LDS dest, inverse-swizzled source
// (verified pair from R2: src col element = ((lane&7)^(lane>>3))*8).
// DEPTH=2: stage A(t+1)@p1, B(t+1)@p2, single vmcnt(0)@p4 (loads 2-3 phases old).
// DEPTH=3: stage all of (t+2)@p1, counted vmcnt(6)@p2 -- never drains mid-loop.
// ---------------------------------------------------------------------------
template<int BM, int BN, int BIAS_MODE, bool RESID, typename OUT_T>
__global__ __launch_bounds__(512, 2) void gemmp(
    const f16* __restrict__ A, size_t sA,
    const f16* __restrict__ B, size_t sB,
    OUT_T* __restrict__ Co, size_t sC,
    const float* __restrict__ resid, size_t sR,
    const float* __restrict__ bias,
    int K, int lda, int ldb, int ldc, float alpha)
{
    constexpr int NWR = (BM == 256 && BN == 128) ? 4 : 2;
    constexpr int NWC = 8 / NWR;
    constexpr int RPW = BM / NWR;       // 128 or 64
    constexpr int CPW = BN / NWC;       // 64
    constexpr int MF  = RPW / 16;       // 8 or 4
    constexpr int AU  = BM / 64;        // 8KB stage units
    constexpr int BU  = BN / 64;
    constexpr int DEPTH = (MF == 8) ? 2 : 3;
    constexpr int TILEA = BM * 128;     // bytes per K-tile of A
    constexpr int TILEB = BN * 128;
    constexpr int TILE  = TILEA + TILEB;

    __shared__ char lds[DEPTH * TILE];

    const int tid = threadIdx.x, lane = tid & 63, w = tid >> 6;
    const int l15 = lane & 15, lhi = lane >> 4;
    const int wr = w / NWC, wc = w % NWC;
    const int bm = blockIdx.y, bn = blockIdx.x, bz = blockIdx.z;

    A  += (size_t)bz * sA + (size_t)(bm * BM) * lda;
    B  += (size_t)bz * sB + (size_t)(bn * BN) * ldb;
    Co += (size_t)bz * sC;

    f32x4 acc[MF][4] = {};

    const int srcColE = ((lane & 7) ^ (lane >> 3)) * 8;
    const int srowOff = w * 8 + (lane >> 3);   // + u*64

    auto STAGE_A = [&](int t) {
        char* dst = lds + (t % DEPTH) * TILE;
        const f16* src = A + t * 64 + srcColE;
#pragma unroll
        for (int u = 0; u < AU; ++u)
            gload_lds16(src + (size_t)(u * 64 + srowOff) * lda,
                        (f16*)(dst + u * 8192 + w * 1024));
    };
    auto STAGE_B = [&](int t) {
        char* dst = lds + (t % DEPTH) * TILE + TILEA;
        const f16* src = B + t * 64 + srcColE;
#pragma unroll
        for (int u = 0; u < BU; ++u)
            gload_lds16(src + (size_t)(u * 64 + srowOff) * ldb,
                        (f16*)(dst + u * 8192 + w * 1024));
    };

    const int NT = K >> 6;

    if constexpr (MF == 8) {
        // ---- prologue: tile 0, full drain once
        STAGE_A(0); STAGE_B(0);
        asm volatile("s_waitcnt vmcnt(0)" ::: "memory");
        __builtin_amdgcn_s_barrier();
        __builtin_amdgcn_sched_barrier(0);

        f16x8 af[4][2], bf[2][2], bs[2][2];
        for (int t = 0; t < NT; ++t) {
            const char* cA = lds + (t & 1) * TILE;
            const char* cB = cA + TILEA;
            const bool st = (t < NT - 1);
            // ---- phase 1: {m0-3 x n0-1}, stage A(t+1)
#pragma unroll
            for (int m = 0; m < 4; ++m)
#pragma unroll
                for (int kk = 0; kk < 2; ++kk)
                    af[m][kk] = rd_swz(cA, wr * RPW + m * 16 + l15, kk * 64 + lhi * 16);
#pragma unroll
            for (int n = 0; n < 2; ++n)
#pragma unroll
                for (int kk = 0; kk < 2; ++kk)
                    bf[n][kk] = rd_swz(cB, wc * CPW + n * 16 + l15, kk * 64 + lhi * 16);
            if (st) STAGE_A(t + 1);
            __builtin_amdgcn_s_barrier();
            asm volatile("s_waitcnt lgkmcnt(0)" ::: "memory");
            __builtin_amdgcn_sched_barrier(0);
            __builtin_amdgcn_s_setprio(1);
#pragma unroll
            for (int m = 0; m < 4; ++m)
#pragma unroll
                for (int n = 0; n < 2; ++n)
#pragma unroll
                    for (int kk = 0; kk < 2; ++kk)
                        acc[m][n] = __builtin_amdgcn_mfma_f32_16x16x32_f16(
                            af[m][kk], bf[n][kk], acc[m][n], 0, 0, 0);
            __builtin_amdgcn_s_setprio(0);
            __builtin_amdgcn_s_barrier();
            __builtin_amdgcn_sched_barrier(0);
            // ---- phase 2: {m0-3 x n2-3}, stage B(t+1)
#pragma unroll
            for (int n = 0; n < 2; ++n)
#pragma unroll
                for (int kk = 0; kk < 2; ++kk)
                    bs[n][kk] = rd_swz(cB, wc * CPW + (n + 2) * 16 + l15, kk * 64 + lhi * 16);
            if (st) STAGE_B(t + 1);
            __builtin_amdgcn_s_barrier();
            asm volatile("s_waitcnt lgkmcnt(0)" ::: "memory");
            __builtin_amdgcn_sched_barrier(0);
            __builtin_amdgcn_s_setprio(1);
#pragma unroll
            for (int m = 0; m < 4; ++m)
#pragma unroll
                for (int n = 0; n < 2; ++n)
#pragma unroll
                    for (int kk = 0; kk < 2; ++kk)
                        acc[m][n + 2] = __builtin_amdgcn_mfma_f32_16x16x32_f16(
                            af[m][kk], bs[n][kk], acc[m][n + 2], 0, 0, 0);
            __builtin_amdgcn_s_setprio(0);
            __builtin_amdgcn_s_barrier();
            __builtin_amdgcn_sched_barrier(0);
            // ---- phase 3: {m4-7 x n0-1}
#pragma unroll
            for (int m = 0; m < 4; ++m)
#pragma unroll
                for (int kk = 0; kk < 2; ++kk)
                    af[m][kk] = rd_swz(cA, wr * RPW + (m + 4) * 16 + l15, kk * 64 + lhi * 16);
            __builtin_amdgcn_s_barrier();
            asm volatile("s_waitcnt lgkmcnt(0)" ::: "memory");
            __builtin_amdgcn_sched_barrier(0);
            __builtin_amdgcn_s_setprio(1);
#pragma unroll
            for (int m = 0; m < 4; ++m)
#pragma unroll
                for (int n = 0; n < 2; ++n)
#pragma unroll
                    for (int kk = 0; kk < 2; ++kk)
                        acc[m + 4][n] = __builtin_amdgcn_mfma_f32_16x16x32_f16(
                            af[m][kk], bf[n][kk], acc[m + 4][n], 0, 0, 0);
            __builtin_amdgcn_s_setprio(0);
            __builtin_amdgcn_s_barrier();
            __builtin_amdgcn_sched_barrier(0);
            // ---- phase 4: {m4-7 x n2-3}, then single per-tile drain
            __builtin_amdgcn_s_setprio(1);
#pragma unroll
            for (int m = 0; m < 4; ++m)
#pragma unroll
                for (int n = 0; n < 2; ++n)
#pragma unroll
                    for (int kk = 0; kk < 2; ++kk)
                        acc[m + 4][n + 2] = __builtin_amdgcn_mfma_f32_16x16x32_f16(
                            af[m][kk], bs[n][kk], acc[m + 4][n + 2], 0, 0, 0);
            __builtin_amdgcn_s_setprio(0);
            asm volatile("s_waitcnt vmcnt(0)" ::: "memory");
            __builtin_amdgcn_s_barrier();
            __builtin_amdgcn_sched_barrier(0);
        }
    } else {
        // ---- MF==4: triple-buffer, 2-deep prefetch, counted vmcnt(6)
        STAGE_A(0); STAGE_B(0);
        STAGE_A(1); STAGE_B(1);
        asm volatile("s_waitcnt vmcnt(6)" ::: "memory");
        __builtin_amdgcn_s_barrier();
        __builtin_amdgcn_sched_barrier(0);

        f16x8 af[4][2], bf[2][2], bs[2][2];
        for (int t = 0; t < NT; ++t) {
            const char* cA = lds + (t % 3) * TILE;
            const char* cB = cA + TILEA;
            // ---- phase 1: {m0-3 x n0-1}, stage all of t+2
#pragma unroll
            for (int m = 0; m < 4; ++m)
#pragma unroll
                for (int kk = 0; kk < 2; ++kk)
                    af[m][kk] = rd_swz(cA, wr * RPW + m * 16 + l15, kk * 64 + lhi * 16);
#pragma unroll
            for (int n = 0; n < 2; ++n)
#pragma unroll
                for (int kk = 0; kk < 2; ++kk)
                    bf[n][kk] = rd_swz(cB, wc * CPW + n * 16 + l15, kk * 64 + lhi * 16);
            if (t <= NT - 3) { STAGE_A(t + 2); STAGE_B(t + 2); }
            __builtin_amdgcn_s_barrier();
            asm volatile("s_waitcnt lgkmcnt(0)" ::: "memory");
            __builtin_amdgcn_sched_barrier(0);
            __builtin_amdgcn_s_setprio(1);
#pragma unroll
            for (int m = 0; m < 4; ++m)
#pragma unroll
                for (int n = 0; n < 2; ++n)
#pragma unroll
                    for (int kk = 0; kk < 2; ++kk)
                        acc[m][n] = __builtin_amdgcn_mfma_f32_16x16x32_f16(
                            af[m][kk], bf[n][kk], acc[m][n], 0, 0, 0);
            __builtin_amdgcn_s_setprio(0);
            __builtin_amdgcn_s_barrier();
            __builtin_amdgcn_sched_barrier(0);
            // ---- phase 2: {m0-3 x n2-3}, counted wait for tile t+1
#pragma unroll
            for (int n = 0; n < 2; ++n)
#pragma unroll
                for (int kk = 0; kk < 2; ++kk)
                    bs[n][kk] = rd_swz(cB, wc * CPW + (n + 2) * 16 + l15, kk * 64 + lhi * 16);
            __builtin_amdgcn_s_barrier();
            asm volatile("s_waitcnt lgkmcnt(0)" ::: "memory");
            __builtin_amdgcn_sched_barrier(0);
            __builtin_amdgcn_s_setprio(1);
#pragma unroll
            for (int m = 0; m < 4; ++m)
#pragma unroll
                for (int n = 0; n < 2; ++n)
#pragma unroll
                    for (int kk = 0; kk < 2; ++kk)
                        acc[m][n + 2] = __builtin_amdgcn_mfma_f32_16x16x32_f16(
                            af[m][kk], bs[n][kk], acc[m][n + 2], 0, 0, 0);
            __builtin_amdgcn_s_setprio(0);
            if (t <= NT - 3)      asm volatile("s_waitcnt vmcnt(6)" ::: "memory");
            else if (t == NT - 2) asm volatile("s_waitcnt vmcnt(0)" ::: "memory");
            __builtin_amdgcn_s_barrier();
            __builtin_amdgcn_sched_barrier(0);
        }
    }

    // epilogue
#pragma unroll
    for (int m = 0; m < MF; ++m) {
#pragma unroll
        for (int n = 0; n < 4; ++n) {
            int col = bn * BN + wc * CPW + n * 16 + l15;
#pragma unroll
            for (int r = 0; r < 4; ++r) {
                int row = bm * BM + wr * RPW + m * 16 + lhi * 4 + r;
                float v = acc[m][n][r] * alpha;
                if (BIAS_MODE == 1) v += bias[row];
                if (BIAS_MODE == 2) v += bias[col];
                if (RESID) v += resid[(size_t)bz * sR + (size_t)row * ldc + col];
                Co[(size_t)row * ldc + col] = (OUT_T)v;
            }
        }
    }
}

// ---------------------------------------------------------------------------
// Weight conversion: fp32 -> f16, build [qw;kw] stack and [qb;kb] concat
// ---------------------------------------------------------------------------
__global__ __launch_bounds__(256) void convert_w(
    const float* __restrict__ qw, const float* __restrict__ kw,
    const float* __restrict__ vw, const float* __restrict__ pw,
    const float* __restrict__ qb, const float* __restrict__ kb,
    f16* __restrict__ Wqk, f16* __restrict__ Wv, f16* __restrict__ Wp,
    float* __restrict__ qkb)
{
    int i = blockIdx.x * 256 + threadIdx.x;
    if (i < CC * CC) {
        Wqk[i]           = (f16)qw[i];
        Wqk[CC * CC + i] = (f16)kw[i];
        Wv[i]            = (f16)vw[i];
        Wp[i]            = (f16)pw[i];
    }
    if (i < CC) { qkb[i] = qb[i]; qkb[CC + i] = kb[i]; }
}

// ---------------------------------------------------------------------------
// GroupNorm stage A: partial sums per (b, g, slice)
// ---------------------------------------------------------------------------
__global__ __launch_bounds__(256) void gn_partial(
    const float* __restrict__ x, float2* __restrict__ part)
{
    int s = blockIdx.x, g = blockIdx.y, b = blockIdx.z;
    const float4* p = (const float4*)(x + (size_t)b * CC * LL + (size_t)g * CPG * LL
                                        + (size_t)s * 8192);
    float sum = 0.f, sq = 0.f;
    for (int i = threadIdx.x; i < 2048; i += 256) {
        float4 v = p[i];
        sum += v.x + v.y + v.z + v.w;
        sq  += v.x * v.x + v.y * v.y + v.z * v.z + v.w * v.w;
    }
    for (int o = 32; o; o >>= 1) { sum += __shfl_xor(sum, o); sq += __shfl_xor(sq, o); }
    __shared__ float2 red[4];
    int wave = threadIdx.x >> 6, lane = threadIdx.x & 63;
    if (lane == 0) red[wave] = make_float2(sum, sq);
    __syncthreads();
    if (threadIdx.x == 0) {
        float S = red[0].x + red[1].x + red[2].x + red[3].x;
        float Q = red[0].y + red[1].y + red[2].y + red[3].y;
        part[((size_t)b * GG + g) * 32 + s] = make_float2(S, Q);
    }
}

__global__ void gn_finalize(const float2* __restrict__ part, float2* __restrict__ stats)
{
    int t = threadIdx.x;
    if (t < BB * GG) {
        float s = 0.f, q = 0.f;
        for (int i = 0; i < 32; ++i) { float2 p = part[t * 32 + i]; s += p.x; q += p.y; }
        const float invN = 1.0f / (float)(CPG * LL);
        float mean = s * invN;
        float var  = q * invN - mean * mean;
        stats[t] = make_float2(mean, rsqrtf(var + 1e-6f));
    }
}

// GroupNorm normalize + affine + TRANSPOSE: x [C,L] fp32 -> xnT [L,C] f16
__global__ __launch_bounds__(256) void gn_norm_t(
    const float* __restrict__ x, const float2* __restrict__ stats,
    const float* __restrict__ gw, const float* __restrict__ gb,
    f16* __restrict__ xnT)
{
    __shared__ float t[64][65];
    int l0 = blockIdx.x * 64, c0 = blockIdx.y * 64, b = blockIdx.z;
    float2 st = stats[b * GG + (c0 >> 7)];
    const float* xb = x + (size_t)b * CC * LL;
    for (int i = threadIdx.x; i < 4096; i += 256) {
        int c = i >> 6, l = i & 63;
        float v = xb[(size_t)(c0 + c) * LL + l0 + l];
        t[c][l] = (v - st.x) * st.y * gw[c0 + c] + gb[c0 + c];
    }
    __syncthreads();
    f16* o = xnT + (size_t)b * LL * CC;
    for (int i = threadIdx.x; i < 4096; i += 256) {
        int l = i >> 6, c = i & 63;
        o[(size_t)(l0 + l) * CC + c0 + c] = (f16)t[c][l];
    }
}

// ---------------------------------------------------------------------------
// Row softmax in-place on f16 P [L, L] per (b, row). grid (LL, BB), block 256.
// ---------------------------------------------------------------------------
__global__ __launch_bounds__(256) void softmax_rows(f16* __restrict__ P)
{
    int i = blockIdx.x, b = blockIdx.y;
    f16* row = P + ((size_t)b * LL + (size_t)i) * LL;
    int tid = threadIdx.x;
    f16x8 v = ((const f16x8*)row)[tid];
    float f[8], mx = -1e30f;
#pragma unroll
    for (int j = 0; j < 8; ++j) { f[j] = (float)v[j]; mx = fmaxf(mx, f[j]); }
    for (int o = 32; o; o >>= 1) mx = fmaxf(mx, __shfl_xor(mx, o));
    __shared__ float red1[4];
    __shared__ float red2[4];
    int wave = tid >> 6, lane = tid & 63;
    if (lane == 0) red1[wave] = mx;
    __syncthreads();
    mx = fmaxf(fmaxf(red1[0], red1[1]), fmaxf(red1[2], red1[3]));
    float s = 0.f;
#pragma unroll
    for (int j = 0; j < 8; ++j) { f[j] = __expf(f[j] - mx); s += f[j]; }
    for (int o = 32; o; o >>= 1) s += __shfl_xor(s, o);
    if (lane == 0) red2[wave] = s;
    __syncthreads();
    s = red2[0] + red2[1] + red2[2] + red2[3];
    float inv = 1.0f / s;
    f16x8 o8;
#pragma unroll
    for (int j = 0; j < 8; ++j) o8[j] = (f16)(f[j] * inv);
    ((f16x8*)row)[tid] = o8;
}

// Fallback marker if workspace is too small (distinct absmax signal ~12345)
__global__ void fill_marker(float* out, int n)
{
    int i = blockIdx.x * 256 + threadIdx.x;
    if (i < n) out[i] = 12345.0f;
}

// ---------------------------------------------------------------------------
extern "C" void kernel_launch(void* const* d_in, const int* in_sizes, int n_in,
                              void* d_out, int out_size, void* d_ws, size_t ws_size,
                              hipStream_t stream)
{
    const float* x  = (const float*)d_in[0];
    const float* gw = (const float*)d_in[1];
    const float* gb = (const float*)d_in[2];
    const float* qw = (const float*)d_in[3];
    const float* qb = (const float*)d_in[4];
    const float* kw = (const float*)d_in[5];
    const float* kb = (const float*)d_in[6];
    const float* vw = (const float*)d_in[7];
    const float* vb = (const float*)d_in[8];
    const float* pw = (const float*)d_in[9];
    const float* pb = (const float*)d_in[10];
    float* out = (float*)d_out;

    // workspace layout (bytes)
    char* w = (char*)d_ws;
    float2* part  = (float2*)w;                       //   8 KB
    float2* stats = (float2*)(w + 8192);              //   256 B
    f16* Wqk  = (f16*)(w + 16384);                    //   1 MB   [1024,512]
    f16* Wv   = Wqk + (size_t)1024 * CC;              // 512 KB   [512,512]
    f16* Wp   = Wv  + (size_t)CC * CC;                // 512 KB
    float* qkb = (float*)(Wp + (size_t)CC * CC);      //   4 KB
    f16* xnT  = (f16*)((char*)qkb + 4096);            // 16 MB    [B][L,C]
    f16* QK   = xnT + (size_t)BB * LL * CC;           // 32 MB    [B][L,1024]
    f16* Vm   = QK  + (size_t)BB * LL * 1024;         // 16 MB    [B][C,L]
    f16* Pm   = Vm  + (size_t)BB * CC * LL;           // 64 MB    [B][L,L]
    f16* O2   = xnT;  // alias: xnT dead after gemm2  //          [B][L,C]
    size_t need = (size_t)((char*)(Pm + (size_t)BB * LL * LL) - w);
    if (ws_size < need) {
        fill_marker<<<(out_size + 255) / 256, 256, 0, stream>>>(out, out_size);
        return;
    }

    convert_w<<<dim3((CC * CC + 255) / 256), 256, 0, stream>>>(
        qw, kw, vw, pw, qb, kb, Wqk, Wv, Wp, qkb);
    gn_partial<<<dim3(32, GG, BB), 256, 0, stream>>>(x, part);
    gn_finalize<<<1, 64, 0, stream>>>(part, stats);
    gn_norm_t<<<dim3(LL / 64, CC / 64, BB), 256, 0, stream>>>(x, stats, gw, gb, xnT);

    // GEMM1: [Q|K]t[l, n] = xnT[l,:] . Wqk[n,:] + qkb[n]     (M=L, N=1024, K=C)
    gemmp<256, 256, 2, false, f16><<<dim3(4, 8, BB), 512, 0, stream>>>(
        xnT, (size_t)LL * CC, Wqk, 0, QK, (size_t)LL * 1024, nullptr, 0, qkb,
        CC, CC, CC, 1024, 1.0f);

    // GEMM2: V[c, l] = Wv[c,:] . xnT[l,:] + vb[c]            (M=C, N=L, K=C)
    gemmp<128, 256, 1, false, f16><<<dim3(8, 4, BB), 512, 0, stream>>>(
        Wv, 0, xnT, (size_t)LL * CC, Vm, (size_t)CC * LL, nullptr, 0, vb,
        CC, CC, CC, LL, 1.0f);

    // GEMM3: S[i, j] = scale * Qt[i,:] . Kt[j,:]             (M=L, N=L, K=C)
    gemmp<256, 256, 0, false, f16><<<dim3(8, 8, BB), 512, 0, stream>>>(
        QK, (size_t)LL * 1024, QK + CC, (size_t)LL * 1024, Pm, (size_t)LL * LL,
        nullptr, 0, nullptr,
        CC, 1024, 1024, LL, 0.04419417382415922f);

    softmax_rows<<<dim3(LL, BB), 256, 0, stream>>>(Pm);

    // GEMM4: O2[i, c] = P[i,:] . V[c,:]                      (M=L, N=C, K=L)
    gemmp<256, 128, 0, false, f16><<<dim3(4, 8, BB), 512, 0, stream>>>(
        Pm, (size_t)LL * LL, Vm, (size_t)CC * LL, O2, (size_t)LL * CC,
        nullptr, 0, nullptr,
        LL, LL, LL, CC, 1.0f);

    // GEMM5: out[c, l] = Wp[c,:] . O2[l,:] + pb[c] + x[c,l]  (M=C, N=L, K=C)
    gemmp<128, 256, 1, true, float><<<dim3(8, 4, BB), 512, 0, stream>>>(
        Wp, 0, O2, (size_t)LL * CC, out, (size_t)CC * LL, x, (size_t)CC * LL, pb,
        CC, CC, CC, LL, 1.0f);
}

// Round 6
// 196.041 us; speedup vs baseline: 1.1512x; 1.0563x over previous
//
#include <hip/hip_runtime.h>

#define BB 8
#define CC 512
#define LL 2048
#define GG 4
#define CPG 128   // channels per group

typedef _Float16 f16;
typedef _Float16 f16x8 __attribute__((ext_vector_type(8)));
typedef float f32x4 __attribute__((ext_vector_type(4)));

__device__ __forceinline__ void gload_lds16(const f16* g, f16* l)
{
    __builtin_amdgcn_global_load_lds(
        (__attribute__((address_space(1))) void*)g,
        (__attribute__((address_space(3))) void*)l, 16, 0, 0);
}

// ---------------------------------------------------------------------------
// Weight conversion: fp32 -> f16, build [qw;kw] stack and [qb;kb] concat
// ---------------------------------------------------------------------------
__global__ __launch_bounds__(256) void convert_w(
    const float* __restrict__ qw, const float* __restrict__ kw,
    const float* __restrict__ vw, const float* __restrict__ pw,
    const float* __restrict__ qb, const float* __restrict__ kb,
    f16* __restrict__ Wqk, f16* __restrict__ Wv, f16* __restrict__ Wp,
    float* __restrict__ qkb)
{
    int i = blockIdx.x * 256 + threadIdx.x;
    if (i < CC * CC) {
        Wqk[i]           = (f16)qw[i];
        Wqk[CC * CC + i] = (f16)kw[i];
        Wv[i]            = (f16)vw[i];
        Wp[i]            = (f16)pw[i];
    }
    if (i < CC) { qkb[i] = qb[i]; qkb[CC + i] = kb[i]; }
}

// ---------------------------------------------------------------------------
// GroupNorm stage A: partial sums per (b, g, slice)
// ---------------------------------------------------------------------------
__global__ __launch_bounds__(256) void gn_partial(
    const float* __restrict__ x, float2* __restrict__ part)
{
    int s = blockIdx.x, g = blockIdx.y, b = blockIdx.z;
    const float4* p = (const float4*)(x + (size_t)b * CC * LL + (size_t)g * CPG * LL
                                        + (size_t)s * 8192);
    float sum = 0.f, sq = 0.f;
    for (int i = threadIdx.x; i < 2048; i += 256) {
        float4 v = p[i];
        sum += v.x + v.y + v.z + v.w;
        sq  += v.x * v.x + v.y * v.y + v.z * v.z + v.w * v.w;
    }
    for (int o = 32; o; o >>= 1) { sum += __shfl_xor(sum, o); sq += __shfl_xor(sq, o); }
    __shared__ float2 red[4];
    int wave = threadIdx.x >> 6, lane = threadIdx.x & 63;
    if (lane == 0) red[wave] = make_float2(sum, sq);
    __syncthreads();
    if (threadIdx.x == 0) {
        float S = red[0].x + red[1].x + red[2].x + red[3].x;
        float Q = red[0].y + red[1].y + red[2].y + red[3].y;
        part[((size_t)b * GG + g) * 32 + s] = make_float2(S, Q);
    }
}

__global__ void gn_finalize(const float2* __restrict__ part, float2* __restrict__ stats)
{
    int t = threadIdx.x;
    if (t < BB * GG) {
        float s = 0.f, q = 0.f;
        for (int i = 0; i < 32; ++i) { float2 p = part[t * 32 + i]; s += p.x; q += p.y; }
        const float invN = 1.0f / (float)(CPG * LL);
        float mean = s * invN;
        float var  = q * invN - mean * mean;
        stats[t] = make_float2(mean, rsqrtf(var + 1e-6f));
    }
}

// GroupNorm normalize + affine + TRANSPOSE: x [C,L] fp32 -> xnT [L,C] f16
__global__ __launch_bounds__(256) void gn_norm_t(
    const float* __restrict__ x, const float2* __restrict__ stats,
    const float* __restrict__ gw, const float* __restrict__ gb,
    f16* __restrict__ xnT)
{
    __shared__ float t[64][65];
    int l0 = blockIdx.x * 64, c0 = blockIdx.y * 64, b = blockIdx.z;
    float2 st = stats[b * GG + (c0 >> 7)];
    const float* xb = x + (size_t)b * CC * LL;
    for (int i = threadIdx.x; i < 4096; i += 256) {
        int c = i >> 6, l = i & 63;
        float v = xb[(size_t)(c0 + c) * LL + l0 + l];
        t[c][l] = (v - st.x) * st.y * gw[c0 + c] + gb[c0 + c];
    }
    __syncthreads();
    f16* o = xnT + (size_t)b * LL * CC;
    for (int i = threadIdx.x; i < 4096; i += 256) {
        int l = i >> 6, c = i & 63;
        o[(size_t)(l0 + l) * CC + c0 + c] = (f16)t[c][l];
    }
}

// ---------------------------------------------------------------------------
// Generic batched GEMM  C[M,N] = alpha * A[M,K] · B[N,K]^T (+bias)(+resid)
// R2-proven core: 128x128 tile, BK=64, 4 waves (2x2), 4x4 frags,
// global_load_lds w=16 with linear LDS dest + inverse-swizzled source.
// Epilogue modes:
//   BIAS_MODE: 0 none, 1 bias[row], 2 bias[col]
//   RESID:     += resid[row*ldc+col]
//   SOFTEXP:   out = exp(min(v,11)), f16; deterministic per-block row sums
//              -> rowpart[(bz*M + row)*gridDim.x + bn]
//   ROWSCALE:  v *= rsinv[bz*M + row]   (deferred softmax normalization)
// ---------------------------------------------------------------------------
template<int BIAS_MODE, bool RESID, bool SOFTEXP, bool ROWSCALE, typename OUT_T>
__global__ __launch_bounds__(256) void gemm_bt(
    const f16* __restrict__ A, size_t sA,
    const f16* __restrict__ B, size_t sB,
    OUT_T* __restrict__ Co, size_t sC,
    const float* __restrict__ resid, size_t sR,
    const float* __restrict__ bias,
    float* __restrict__ rowpart, const float* __restrict__ rsinv,
    int M, int N, int K, int lda, int ldb, int ldc, float alpha)
{
    const int tid  = threadIdx.x;
    const int lane = tid & 63;
    const int wave = tid >> 6;
    const int wr = wave >> 1, wc = wave & 1;
    const int l15 = lane & 15, lhi = lane >> 4;
    const int bm = blockIdx.y, bn = blockIdx.x, bz = blockIdx.z;

    A  += (size_t)bz * sA;
    B  += (size_t)bz * sB;
    Co += (size_t)bz * sC;

    __shared__ f16 ldsA[128 * 64];
    __shared__ f16 ldsB[128 * 64];

    f32x4 acc[4][4] = {};

    // staging source column (elements), inverse-swizzled; constant per lane
    const int srcColE = ((lane & 7) ^ (lane >> 3)) * 8;
    const int rowBase = wave * 8 + (lane >> 3);          // + it*32
    const f16* Ag = A + (size_t)(bm * 128 + rowBase) * lda + srcColE;
    const f16* Bg = B + (size_t)(bn * 128 + rowBase) * ldb + srcColE;

    for (int k0 = 0; k0 < K; k0 += 64) {
#pragma unroll
        for (int it = 0; it < 4; ++it) {
            f16* la = (f16*)((char*)ldsA + it * 4096 + wave * 1024);
            f16* lb = (f16*)((char*)ldsB + it * 4096 + wave * 1024);
            gload_lds16(Ag + (size_t)(it * 32) * lda + k0, la);
            gload_lds16(Bg + (size_t)(it * 32) * ldb + k0, lb);
        }
        __syncthreads();
#pragma unroll
        for (int kk = 0; kk < 64; kk += 32) {
            const int kb2 = (kk + lhi * 8) * 2;   // byte col of fragment
            f16x8 af[4], bfr[4];
#pragma unroll
            for (int m = 0; m < 4; ++m) {
                int row = wr * 64 + m * 16 + l15;
                int phys = ((row * 128 + kb2) ^ ((row & 7) << 4)) >> 1;
                af[m] = *(const f16x8*)(ldsA + phys);
            }
#pragma unroll
            for (int n = 0; n < 4; ++n) {
                int row = wc * 64 + n * 16 + l15;
                int phys = ((row * 128 + kb2) ^ ((row & 7) << 4)) >> 1;
                bfr[n] = *(const f16x8*)(ldsB + phys);
            }
#pragma unroll
            for (int m = 0; m < 4; ++m)
#pragma unroll
                for (int n = 0; n < 4; ++n)
                    acc[m][n] = __builtin_amdgcn_mfma_f32_16x16x32_f16(
                        af[m], bfr[n], acc[m][n], 0, 0, 0);
        }
        __syncthreads();
    }

    if constexpr (SOFTEXP) {
        // exp epilogue + deterministic per-block row sums (no atomics)
        __shared__ float rs2[2][128];
        float rowacc[16];
#pragma unroll
        for (int i = 0; i < 16; ++i) rowacc[i] = 0.f;
#pragma unroll
        for (int m = 0; m < 4; ++m) {
#pragma unroll
            for (int n = 0; n < 4; ++n) {
                int col = bn * 128 + wc * 64 + n * 16 + l15;
#pragma unroll
                for (int r = 0; r < 4; ++r) {
                    int row = bm * 128 + wr * 64 + m * 16 + lhi * 4 + r;
                    float e = __expf(fminf(acc[m][n][r] * alpha, 11.0f));
                    rowacc[m * 4 + r] += e;
                    Co[(size_t)row * ldc + col] = (OUT_T)e;
                }
            }
        }
        // butterfly over l15 group (lanes sharing lhi hold the same rows)
#pragma unroll
        for (int off = 1; off < 16; off <<= 1)
#pragma unroll
            for (int i = 0; i < 16; ++i)
                rowacc[i] += __shfl_xor(rowacc[i], off);
        if (l15 == 0) {
#pragma unroll
            for (int i = 0; i < 16; ++i)
                rs2[wc][wr * 64 + (i >> 2) * 16 + lhi * 4 + (i & 3)] = rowacc[i];
        }
        __syncthreads();
        if (tid < 128) {
            int row = bm * 128 + tid;
            rowpart[((size_t)bz * M + row) * gridDim.x + bn] =
                rs2[0][tid] + rs2[1][tid];
        }
    } else {
#pragma unroll
        for (int m = 0; m < 4; ++m) {
#pragma unroll
            for (int n = 0; n < 4; ++n) {
                int col = bn * 128 + wc * 64 + n * 16 + l15;
#pragma unroll
                for (int r = 0; r < 4; ++r) {
                    int row = bm * 128 + wr * 64 + m * 16 + lhi * 4 + r;
                    float v = acc[m][n][r] * alpha;
                    if (BIAS_MODE == 1) v += bias[row];
                    if (BIAS_MODE == 2) v += bias[col];
                    if (ROWSCALE) v *= rsinv[(size_t)bz * M + row];
                    if (RESID) v += resid[(size_t)bz * sR + (size_t)row * ldc + col];
                    Co[(size_t)row * ldc + col] = (OUT_T)v;
                }
            }
        }
    }
}

// ---------------------------------------------------------------------------
// rsinv[b*L + i] = 1 / sum_bn rowpart[(b*L+i)*nbn + bn]     grid 64 x 256
// ---------------------------------------------------------------------------
__global__ __launch_bounds__(256) void rowsum_inv(
    const float* __restrict__ rowpart, float* __restrict__ rsinv, int nbn)
{
    int i = blockIdx.x * 256 + threadIdx.x;
    if (i < BB * LL) {
        float s = 0.f;
        for (int k = 0; k < nbn; ++k) s += rowpart[(size_t)i * nbn + k];
        rsinv[i] = 1.0f / s;
    }
}

// Fallback marker if workspace is too small (distinct absmax signal ~12345)
__global__ void fill_marker(float* out, int n)
{
    int i = blockIdx.x * 256 + threadIdx.x;
    if (i < n) out[i] = 12345.0f;
}

// ---------------------------------------------------------------------------
extern "C" void kernel_launch(void* const* d_in, const int* in_sizes, int n_in,
                              void* d_out, int out_size, void* d_ws, size_t ws_size,
                              hipStream_t stream)
{
    const float* x  = (const float*)d_in[0];
    const float* gw = (const float*)d_in[1];
    const float* gb = (const float*)d_in[2];
    const float* qw = (const float*)d_in[3];
    const float* qb = (const float*)d_in[4];
    const float* kw = (const float*)d_in[5];
    const float* kb = (const float*)d_in[6];
    const float* vw = (const float*)d_in[7];
    const float* vb = (const float*)d_in[8];
    const float* pw = (const float*)d_in[9];
    const float* pb = (const float*)d_in[10];
    float* out = (float*)d_out;

    // workspace layout (bytes)
    char* w = (char*)d_ws;
    float2* part  = (float2*)w;                       //   8 KB
    float2* stats = (float2*)(w + 8192);              //   256 B
    f16* Wqk  = (f16*)(w + 16384);                    //   1 MB   [1024,512]
    f16* Wv   = Wqk + (size_t)1024 * CC;              // 512 KB   [512,512]
    f16* Wp   = Wv  + (size_t)CC * CC;                // 512 KB
    float* qkb = (float*)(Wp + (size_t)CC * CC);      //   4 KB
    f16* xnT  = (f16*)((char*)qkb + 4096);            // 16 MB    [B][L,C]
    f16* QK   = xnT + (size_t)BB * LL * CC;           // 32 MB    [B][L,1024]
    f16* Vm   = QK  + (size_t)BB * LL * 1024;         // 16 MB    [B][C,L]
    f16* Pm   = Vm  + (size_t)BB * CC * LL;           // 64 MB    [B][L,L]
    float* rowpart = (float*)(Pm + (size_t)BB * LL * LL);  // 1 MB  [B*L][16]
    float* rsinv   = rowpart + (size_t)BB * LL * 16;       // 64 KB [B*L]
    f16* O2   = xnT;  // alias: xnT dead after gemm2  //          [B][L,C]
    size_t need = (size_t)((char*)(rsinv + (size_t)BB * LL) - w);
    if (ws_size < need) {
        fill_marker<<<(out_size + 255) / 256, 256, 0, stream>>>(out, out_size);
        return;
    }

    convert_w<<<dim3((CC * CC + 255) / 256), 256, 0, stream>>>(
        qw, kw, vw, pw, qb, kb, Wqk, Wv, Wp, qkb);
    gn_partial<<<dim3(32, GG, BB), 256, 0, stream>>>(x, part);
    gn_finalize<<<1, 64, 0, stream>>>(part, stats);
    gn_norm_t<<<dim3(LL / 64, CC / 64, BB), 256, 0, stream>>>(x, stats, gw, gb, xnT);

    // GEMM1: [Q|K]t[l, n] = xnT[l,:] . Wqk[n,:] + qkb[n]     (M=L, N=1024, K=C)
    gemm_bt<2, false, false, false, f16><<<dim3(1024 / 128, LL / 128, BB), 256, 0, stream>>>(
        xnT, (size_t)LL * CC, Wqk, 0, QK, (size_t)LL * 1024, nullptr, 0, qkb,
        nullptr, nullptr,
        LL, 1024, CC, CC, CC, 1024, 1.0f);

    // GEMM2: V[c, l] = Wv[c,:] . xnT[l,:] + vb[c]            (M=C, N=L, K=C)
    gemm_bt<1, false, false, false, f16><<<dim3(LL / 128, CC / 128, BB), 256, 0, stream>>>(
        Wv, 0, xnT, (size_t)LL * CC, Vm, (size_t)CC * LL, nullptr, 0, vb,
        nullptr, nullptr,
        CC, LL, CC, CC, CC, LL, 1.0f);

    // GEMM3: P'[i, j] = exp(scale * Qt[i,:] . Kt[j,:]) ; rowpart  (M=L, N=L, K=C)
    gemm_bt<0, false, true, false, f16><<<dim3(LL / 128, LL / 128, BB), 256, 0, stream>>>(
        QK, (size_t)LL * 1024, QK + CC, (size_t)LL * 1024, Pm, (size_t)LL * LL,
        nullptr, 0, nullptr,
        rowpart, nullptr,
        LL, LL, CC, 1024, 1024, LL, 0.04419417382415922f);

    rowsum_inv<<<dim3((BB * LL + 255) / 256), 256, 0, stream>>>(rowpart, rsinv, LL / 128);

    // GEMM4: O2[i, c] = (P'[i,:] . V[c,:]) * rsinv[i]        (M=L, N=C, K=L)
    gemm_bt<0, false, false, true, f16><<<dim3(CC / 128, LL / 128, BB), 256, 0, stream>>>(
        Pm, (size_t)LL * LL, Vm, (size_t)CC * LL, O2, (size_t)LL * CC,
        nullptr, 0, nullptr,
        nullptr, rsinv,
        LL, CC, LL, LL, LL, CC, 1.0f);

    // GEMM5: out[c, l] = Wp[c,:] . O2[l,:] + pb[c] + x[c,l]  (M=C, N=L, K=C)
    gemm_bt<1, true, false, false, float><<<dim3(LL / 128, CC / 128, BB), 256, 0, stream>>>(
        Wp, 0, O2, (size_t)LL * CC, out, (size_t)CC * LL, x, (size_t)CC * LL, pb,
        nullptr, nullptr,
        CC, LL, CC, CC, CC, LL, 1.0f);
}

// Round 7
// 195.783 us; speedup vs baseline: 1.1527x; 1.0013x over previous
//
#include <hip/hip_runtime.h>

#define BB 8
#define CC 512
#define LL 2048
#define GG 4
#define CPG 128   // channels per group

typedef _Float16 f16;
typedef _Float16 f16x8 __attribute__((ext_vector_type(8)));
typedef float f32x4 __attribute__((ext_vector_type(4)));

__device__ __forceinline__ void gload_lds16(const f16* g, f16* l)
{
    __builtin_amdgcn_global_load_lds(
        (__attribute__((address_space(1))) void*)g,
        (__attribute__((address_space(3))) void*)l, 16, 0, 0);
}

// ---------------------------------------------------------------------------
// Weight conversion: fp32 -> f16, build [qw;kw] stack and [qb;kb] concat
// ---------------------------------------------------------------------------
__global__ __launch_bounds__(256) void convert_w(
    const float* __restrict__ qw, const float* __restrict__ kw,
    const float* __restrict__ vw, const float* __restrict__ pw,
    const float* __restrict__ qb, const float* __restrict__ kb,
    f16* __restrict__ Wqk, f16* __restrict__ Wv, f16* __restrict__ Wp,
    float* __restrict__ qkb)
{
    int i = blockIdx.x * 256 + threadIdx.x;
    if (i < CC * CC) {
        Wqk[i]           = (f16)qw[i];
        Wqk[CC * CC + i] = (f16)kw[i];
        Wv[i]            = (f16)vw[i];
        Wp[i]            = (f16)pw[i];
    }
    if (i < CC) { qkb[i] = qb[i]; qkb[CC + i] = kb[i]; }
}

// ---------------------------------------------------------------------------
// GroupNorm stage A: partial sums per (b, g, slice)
// ---------------------------------------------------------------------------
__global__ __launch_bounds__(256) void gn_partial(
    const float* __restrict__ x, float2* __restrict__ part)
{
    int s = blockIdx.x, g = blockIdx.y, b = blockIdx.z;
    const float4* p = (const float4*)(x + (size_t)b * CC * LL + (size_t)g * CPG * LL
                                        + (size_t)s * 8192);
    float sum = 0.f, sq = 0.f;
    for (int i = threadIdx.x; i < 2048; i += 256) {
        float4 v = p[i];
        sum += v.x + v.y + v.z + v.w;
        sq  += v.x * v.x + v.y * v.y + v.z * v.z + v.w * v.w;
    }
    for (int o = 32; o; o >>= 1) { sum += __shfl_xor(sum, o); sq += __shfl_xor(sq, o); }
    __shared__ float2 red[4];
    int wave = threadIdx.x >> 6, lane = threadIdx.x & 63;
    if (lane == 0) red[wave] = make_float2(sum, sq);
    __syncthreads();
    if (threadIdx.x == 0) {
        float S = red[0].x + red[1].x + red[2].x + red[3].x;
        float Q = red[0].y + red[1].y + red[2].y + red[3].y;
        part[((size_t)b * GG + g) * 32 + s] = make_float2(S, Q);
    }
}

__global__ void gn_finalize(const float2* __restrict__ part, float2* __restrict__ stats)
{
    int t = threadIdx.x;
    if (t < BB * GG) {
        float s = 0.f, q = 0.f;
        for (int i = 0; i < 32; ++i) { float2 p = part[t * 32 + i]; s += p.x; q += p.y; }
        const float invN = 1.0f / (float)(CPG * LL);
        float mean = s * invN;
        float var  = q * invN - mean * mean;
        stats[t] = make_float2(mean, rsqrtf(var + 1e-6f));
    }
}

// GroupNorm normalize + affine + TRANSPOSE: x [C,L] fp32 -> xnT [L,C] f16
__global__ __launch_bounds__(256) void gn_norm_t(
    const float* __restrict__ x, const float2* __restrict__ stats,
    const float* __restrict__ gw, const float* __restrict__ gb,
    f16* __restrict__ xnT)
{
    __shared__ float t[64][65];
    int l0 = blockIdx.x * 64, c0 = blockIdx.y * 64, b = blockIdx.z;
    float2 st = stats[b * GG + (c0 >> 7)];
    const float* xb = x + (size_t)b * CC * LL;
    for (int i = threadIdx.x; i < 4096; i += 256) {
        int c = i >> 6, l = i & 63;
        float v = xb[(size_t)(c0 + c) * LL + l0 + l];
        t[c][l] = (v - st.x) * st.y * gw[c0 + c] + gb[c0 + c];
    }
    __syncthreads();
    f16* o = xnT + (size_t)b * LL * CC;
    for (int i = threadIdx.x; i < 4096; i += 256) {
        int l = i >> 6, c = i & 63;
        o[(size_t)(l0 + l) * CC + c0 + c] = (f16)t[c][l];
    }
}

// ---------------------------------------------------------------------------
// Batched GEMM  C[M,N] = alpha * A[M,K] · B[N,K]^T (+bias)(+resid)
// Tile 128x256, BK=64, 4 waves (2x2), per-wave 64x128 = acc[4][8]
// (12 ds_read_b128 / 32 MFMA per kk-step; 64 MFMA per wave per K-tile).
// Staging: global_load_lds w=16, linear LDS dest + inverse-swizzled source
// (R2-verified pair). Read swizzle: phys=(row*128+col)^((row&7)<<4), 0-conflict.
// Epilogue modes:
//   BIAS_MODE: 0 none, 1 bias[row], 2 bias[col]
//   RESID:     += resid[row*ldc+col]
//   SOFTEXP:   out = exp(min(v,11)), f16; deterministic per-block row sums
//              -> rowpart[(bz*M + row)*gridDim.x + bn]
//   ROWSCALE:  v *= rsinv[bz*M + row]   (deferred softmax normalization)
// ---------------------------------------------------------------------------
template<int BIAS_MODE, bool RESID, bool SOFTEXP, bool ROWSCALE, typename OUT_T>
__global__ __launch_bounds__(256, 2) void gemm_bt(
    const f16* __restrict__ A, size_t sA,
    const f16* __restrict__ B, size_t sB,
    OUT_T* __restrict__ Co, size_t sC,
    const float* __restrict__ resid, size_t sR,
    const float* __restrict__ bias,
    float* __restrict__ rowpart, const float* __restrict__ rsinv,
    int M, int N, int K, int lda, int ldb, int ldc, float alpha)
{
    const int tid  = threadIdx.x;
    const int lane = tid & 63;
    const int wave = tid >> 6;
    const int wr = wave >> 1, wc = wave & 1;
    const int l15 = lane & 15, lhi = lane >> 4;
    const int bm = blockIdx.y, bn = blockIdx.x, bz = blockIdx.z;

    A  += (size_t)bz * sA;
    B  += (size_t)bz * sB;
    Co += (size_t)bz * sC;

    __shared__ f16 ldsA[128 * 64];
    __shared__ f16 ldsB[256 * 64];

    f32x4 acc[4][8] = {};

    // staging source column (elements), inverse-swizzled; constant per lane
    const int srcColE = ((lane & 7) ^ (lane >> 3)) * 8;
    const int rowBase = wave * 8 + (lane >> 3);          // + it*32
    const f16* Ag = A + (size_t)(bm * 128 + rowBase) * lda + srcColE;
    const f16* Bg = B + (size_t)(bn * 256 + rowBase) * ldb + srcColE;

    for (int k0 = 0; k0 < K; k0 += 64) {
#pragma unroll
        for (int it = 0; it < 4; ++it)
            gload_lds16(Ag + (size_t)(it * 32) * lda + k0,
                        (f16*)((char*)ldsA + it * 4096 + wave * 1024));
#pragma unroll
        for (int it = 0; it < 8; ++it)
            gload_lds16(Bg + (size_t)(it * 32) * ldb + k0,
                        (f16*)((char*)ldsB + it * 4096 + wave * 1024));
        __syncthreads();
#pragma unroll
        for (int kk = 0; kk < 64; kk += 32) {
            const int kb2 = (kk + lhi * 8) * 2;   // byte col of fragment
            f16x8 af[4], bfr[8];
#pragma unroll
            for (int m = 0; m < 4; ++m) {
                int row = wr * 64 + m * 16 + l15;
                int phys = ((row * 128 + kb2) ^ ((row & 7) << 4)) >> 1;
                af[m] = *(const f16x8*)(ldsA + phys);
            }
#pragma unroll
            for (int n = 0; n < 8; ++n) {
                int row = wc * 128 + n * 16 + l15;
                int phys = ((row * 128 + kb2) ^ ((row & 7) << 4)) >> 1;
                bfr[n] = *(const f16x8*)(ldsB + phys);
            }
#pragma unroll
            for (int m = 0; m < 4; ++m)
#pragma unroll
                for (int n = 0; n < 8; ++n)
                    acc[m][n] = __builtin_amdgcn_mfma_f32_16x16x32_f16(
                        af[m], bfr[n], acc[m][n], 0, 0, 0);
        }
        __syncthreads();
    }

    if constexpr (SOFTEXP) {
        // exp epilogue + deterministic per-block row sums (no atomics)
        __shared__ float rs2[2][128];
        float rowacc[16];
#pragma unroll
        for (int i = 0; i < 16; ++i) rowacc[i] = 0.f;
#pragma unroll
        for (int m = 0; m < 4; ++m) {
#pragma unroll
            for (int n = 0; n < 8; ++n) {
                int col = bn * 256 + wc * 128 + n * 16 + l15;
#pragma unroll
                for (int r = 0; r < 4; ++r) {
                    int row = bm * 128 + wr * 64 + m * 16 + lhi * 4 + r;
                    float e = __expf(fminf(acc[m][n][r] * alpha, 11.0f));
                    rowacc[m * 4 + r] += e;
                    Co[(size_t)row * ldc + col] = (OUT_T)e;
                }
            }
        }
        // butterfly over l15 group (lanes sharing lhi hold the same rows)
#pragma unroll
        for (int off = 1; off < 16; off <<= 1)
#pragma unroll
            for (int i = 0; i < 16; ++i)
                rowacc[i] += __shfl_xor(rowacc[i], off);
        if (l15 == 0) {
#pragma unroll
            for (int i = 0; i < 16; ++i)
                rs2[wc][wr * 64 + (i >> 2) * 16 + lhi * 4 + (i & 3)] = rowacc[i];
        }
        __syncthreads();
        if (tid < 128) {
            int row = bm * 128 + tid;
            rowpart[((size_t)bz * M + row) * gridDim.x + bn] =
                rs2[0][tid] + rs2[1][tid];
        }
    } else {
#pragma unroll
        for (int m = 0; m < 4; ++m) {
#pragma unroll
            for (int n = 0; n < 8; ++n) {
                int col = bn * 256 + wc * 128 + n * 16 + l15;
#pragma unroll
                for (int r = 0; r < 4; ++r) {
                    int row = bm * 128 + wr * 64 + m * 16 + lhi * 4 + r;
                    float v = acc[m][n][r] * alpha;
                    if (BIAS_MODE == 1) v += bias[row];
                    if (BIAS_MODE == 2) v += bias[col];
                    if (ROWSCALE) v *= rsinv[(size_t)bz * M + row];
                    if (RESID) v += resid[(size_t)bz * sR + (size_t)row * ldc + col];
                    Co[(size_t)row * ldc + col] = (OUT_T)v;
                }
            }
        }
    }
}

// ---------------------------------------------------------------------------
// rsinv[b*L + i] = 1 / sum_bn rowpart[(b*L+i)*nbn + bn]
// ---------------------------------------------------------------------------
__global__ __launch_bounds__(256) void rowsum_inv(
    const float* __restrict__ rowpart, float* __restrict__ rsinv, int nbn)
{
    int i = blockIdx.x * 256 + threadIdx.x;
    if (i < BB * LL) {
        float s = 0.f;
        for (int k = 0; k < nbn; ++k) s += rowpart[(size_t)i * nbn + k];
        rsinv[i] = 1.0f / s;
    }
}

// Fallback marker if workspace is too small (distinct absmax signal ~12345)
__global__ void fill_marker(float* out, int n)
{
    int i = blockIdx.x * 256 + threadIdx.x;
    if (i < n) out[i] = 12345.0f;
}

// ---------------------------------------------------------------------------
extern "C" void kernel_launch(void* const* d_in, const int* in_sizes, int n_in,
                              void* d_out, int out_size, void* d_ws, size_t ws_size,
                              hipStream_t stream)
{
    const float* x  = (const float*)d_in[0];
    const float* gw = (const float*)d_in[1];
    const float* gb = (const float*)d_in[2];
    const float* qw = (const float*)d_in[3];
    const float* qb = (const float*)d_in[4];
    const float* kw = (const float*)d_in[5];
    const float* kb = (const float*)d_in[6];
    const float* vw = (const float*)d_in[7];
    const float* vb = (const float*)d_in[8];
    const float* pw = (const float*)d_in[9];
    const float* pb = (const float*)d_in[10];
    float* out = (float*)d_out;

    // workspace layout (bytes)
    char* w = (char*)d_ws;
    float2* part  = (float2*)w;                       //   8 KB
    float2* stats = (float2*)(w + 8192);              //   256 B
    f16* Wqk  = (f16*)(w + 16384);                    //   1 MB   [1024,512]
    f16* Wv   = Wqk + (size_t)1024 * CC;              // 512 KB   [512,512]
    f16* Wp   = Wv  + (size_t)CC * CC;                // 512 KB
    float* qkb = (float*)(Wp + (size_t)CC * CC);      //   4 KB
    f16* xnT  = (f16*)((char*)qkb + 4096);            // 16 MB    [B][L,C]
    f16* QK   = xnT + (size_t)BB * LL * CC;           // 32 MB    [B][L,1024]
    f16* Vm   = QK  + (size_t)BB * LL * 1024;         // 16 MB    [B][C,L]
    f16* Pm   = Vm  + (size_t)BB * CC * LL;           // 64 MB    [B][L,L]
    float* rowpart = (float*)(Pm + (size_t)BB * LL * LL);  // 512 KB [B*L][8]
    float* rsinv   = rowpart + (size_t)BB * LL * 8;        // 64 KB  [B*L]
    f16* O2   = xnT;  // alias: xnT dead after gemm2  //          [B][L,C]
    size_t need = (size_t)((char*)(rsinv + (size_t)BB * LL) - w);
    if (ws_size < need) {
        fill_marker<<<(out_size + 255) / 256, 256, 0, stream>>>(out, out_size);
        return;
    }

    convert_w<<<dim3((CC * CC + 255) / 256), 256, 0, stream>>>(
        qw, kw, vw, pw, qb, kb, Wqk, Wv, Wp, qkb);
    gn_partial<<<dim3(32, GG, BB), 256, 0, stream>>>(x, part);
    gn_finalize<<<1, 64, 0, stream>>>(part, stats);
    gn_norm_t<<<dim3(LL / 64, CC / 64, BB), 256, 0, stream>>>(x, stats, gw, gb, xnT);

    // GEMM1: [Q|K]t[l, n] = xnT[l,:] . Wqk[n,:] + qkb[n]     (M=L, N=1024, K=C)
    gemm_bt<2, false, false, false, f16><<<dim3(1024 / 256, LL / 128, BB), 256, 0, stream>>>(
        xnT, (size_t)LL * CC, Wqk, 0, QK, (size_t)LL * 1024, nullptr, 0, qkb,
        nullptr, nullptr,
        LL, 1024, CC, CC, CC, 1024, 1.0f);

    // GEMM2: V[c, l] = Wv[c,:] . xnT[l,:] + vb[c]            (M=C, N=L, K=C)
    gemm_bt<1, false, false, false, f16><<<dim3(LL / 256, CC / 128, BB), 256, 0, stream>>>(
        Wv, 0, xnT, (size_t)LL * CC, Vm, (size_t)CC * LL, nullptr, 0, vb,
        nullptr, nullptr,
        CC, LL, CC, CC, CC, LL, 1.0f);

    // GEMM3: P'[i, j] = exp(scale * Qt[i,:] . Kt[j,:]) ; rowpart  (M=L, N=L, K=C)
    gemm_bt<0, false, true, false, f16><<<dim3(LL / 256, LL / 128, BB), 256, 0, stream>>>(
        QK, (size_t)LL * 1024, QK + CC, (size_t)LL * 1024, Pm, (size_t)LL * LL,
        nullptr, 0, nullptr,
        rowpart, nullptr,
        LL, LL, CC, 1024, 1024, LL, 0.04419417382415922f);

    rowsum_inv<<<dim3((BB * LL + 255) / 256), 256, 0, stream>>>(rowpart, rsinv, LL / 256);

    // GEMM4: O2[i, c] = (P'[i,:] . V[c,:]) * rsinv[i]        (M=L, N=C, K=L)
    gemm_bt<0, false, false, true, f16><<<dim3(CC / 256, LL / 128, BB), 256, 0, stream>>>(
        Pm, (size_t)LL * LL, Vm, (size_t)CC * LL, O2, (size_t)LL * CC,
        nullptr, 0, nullptr,
        nullptr, rsinv,
        LL, CC, LL, LL, LL, CC, 1.0f);

    // GEMM5: out[c, l] = Wp[c,:] . O2[l,:] + pb[c] + x[c,l]  (M=C, N=L, K=C)
    gemm_bt<1, true, false, false, float><<<dim3(LL / 256, CC / 128, BB), 256, 0, stream>>>(
        Wp, 0, O2, (size_t)LL * CC, out, (size_t)CC * LL, x, (size_t)CC * LL, pb,
        nullptr, nullptr,
        CC, LL, CC, CC, CC, LL, 1.0f);
}

// Round 8
// 162.251 us; speedup vs baseline: 1.3909x; 1.2067x over previous
//
#include <hip/hip_runtime.h>

#define BB 8
#define CC 512
#define LL 2048
#define GG 4
#define CPG 128   // channels per group

typedef _Float16 f16;
typedef _Float16 f16x8 __attribute__((ext_vector_type(8)));
typedef float f32x4 __attribute__((ext_vector_type(4)));

__device__ __forceinline__ void gload_lds16(const f16* g, f16* l)
{
    __builtin_amdgcn_global_load_lds(
        (__attribute__((address_space(1))) void*)g,
        (__attribute__((address_space(3))) void*)l, 16, 0, 0);
}

// ---------------------------------------------------------------------------
// Weight conversion: fp32 -> f16, build [qw;kw] stack and [qb;kb] concat
// ---------------------------------------------------------------------------
__global__ __launch_bounds__(256) void convert_w(
    const float* __restrict__ qw, const float* __restrict__ kw,
    const float* __restrict__ vw, const float* __restrict__ pw,
    const float* __restrict__ qb, const float* __restrict__ kb,
    f16* __restrict__ Wqk, f16* __restrict__ Wv, f16* __restrict__ Wp,
    float* __restrict__ qkb)
{
    int i = blockIdx.x * 256 + threadIdx.x;
    if (i < CC * CC) {
        Wqk[i]           = (f16)qw[i];
        Wqk[CC * CC + i] = (f16)kw[i];
        Wv[i]            = (f16)vw[i];
        Wp[i]            = (f16)pw[i];
    }
    if (i < CC) { qkb[i] = qb[i]; qkb[CC + i] = kb[i]; }
}

// ---------------------------------------------------------------------------
// GroupNorm stage A: partial sums per (b, g, slice)
// ---------------------------------------------------------------------------
__global__ __launch_bounds__(256) void gn_partial(
    const float* __restrict__ x, float2* __restrict__ part)
{
    int s = blockIdx.x, g = blockIdx.y, b = blockIdx.z;
    const float4* p = (const float4*)(x + (size_t)b * CC * LL + (size_t)g * CPG * LL
                                        + (size_t)s * 8192);
    float sum = 0.f, sq = 0.f;
    for (int i = threadIdx.x; i < 2048; i += 256) {
        float4 v = p[i];
        sum += v.x + v.y + v.z + v.w;
        sq  += v.x * v.x + v.y * v.y + v.z * v.z + v.w * v.w;
    }
    for (int o = 32; o; o >>= 1) { sum += __shfl_xor(sum, o); sq += __shfl_xor(sq, o); }
    __shared__ float2 red[4];
    int wave = threadIdx.x >> 6, lane = threadIdx.x & 63;
    if (lane == 0) red[wave] = make_float2(sum, sq);
    __syncthreads();
    if (threadIdx.x == 0) {
        float S = red[0].x + red[1].x + red[2].x + red[3].x;
        float Q = red[0].y + red[1].y + red[2].y + red[3].y;
        part[((size_t)b * GG + g) * 32 + s] = make_float2(S, Q);
    }
}

__global__ void gn_finalize(const float2* __restrict__ part, float2* __restrict__ stats)
{
    int t = threadIdx.x;
    if (t < BB * GG) {
        float s = 0.f, q = 0.f;
        for (int i = 0; i < 32; ++i) { float2 p = part[t * 32 + i]; s += p.x; q += p.y; }
        const float invN = 1.0f / (float)(CPG * LL);
        float mean = s * invN;
        float var  = q * invN - mean * mean;
        stats[t] = make_float2(mean, rsqrtf(var + 1e-6f));
    }
}

// GroupNorm normalize + affine + TRANSPOSE: x [C,L] fp32 -> xnT [L,C] f16
__global__ __launch_bounds__(256) void gn_norm_t(
    const float* __restrict__ x, const float2* __restrict__ stats,
    const float* __restrict__ gw, const float* __restrict__ gb,
    f16* __restrict__ xnT)
{
    __shared__ float t[64][65];
    int l0 = blockIdx.x * 64, c0 = blockIdx.y * 64, b = blockIdx.z;
    float2 st = stats[b * GG + (c0 >> 7)];
    const float* xb = x + (size_t)b * CC * LL;
    for (int i = threadIdx.x; i < 4096; i += 256) {
        int c = i >> 6, l = i & 63;
        float v = xb[(size_t)(c0 + c) * LL + l0 + l];
        t[c][l] = (v - st.x) * st.y * gw[c0 + c] + gb[c0 + c];
    }
    __syncthreads();
    f16* o = xnT + (size_t)b * LL * CC;
    for (int i = threadIdx.x; i < 4096; i += 256) {
        int l = i >> 6, c = i & 63;
        o[(size_t)(l0 + l) * CC + c0 + c] = (f16)t[c][l];
    }
}

// ---------------------------------------------------------------------------
// Batched GEMM  C[M,N] = alpha * A[M,K] · B[N,K]^T (+bias)(+resid)
// Tile 128 x (NBT*32), BK=64, 4 waves (2x2), per-wave 64 x (NBT*16).
//   NBT=4: 128x128 (proven R2 core, 32KB LDS), NBT=8: 128x256 (48KB LDS).
// Staging: global_load_lds w=16, linear LDS dest + inverse-swizzled source.
// Read swizzle: phys=(row*128+col)^((row&7)<<4), measured 0-conflict.
// XCD-aware bijective block swizzle (T1): logical = (hw&7)*(nwg/8) + hw>>3,
// so each XCD's resident blocks share one batch's A/B panels in its L2.
// Epilogue modes: BIAS_MODE 0/1(row)/2(col); RESID; SOFTEXP (exp + row sums);
// ROWSCALE (deferred softmax normalization).
// ---------------------------------------------------------------------------
template<int NBT, int BIAS_MODE, bool RESID, bool SOFTEXP, bool ROWSCALE, typename OUT_T>
__global__ __launch_bounds__(256, 2) void gemm_bt(
    const f16* __restrict__ A, size_t sA,
    const f16* __restrict__ B, size_t sB,
    OUT_T* __restrict__ Co, size_t sC,
    const float* __restrict__ resid, size_t sR,
    const float* __restrict__ bias,
    float* __restrict__ rowpart, const float* __restrict__ rsinv,
    int M, int N, int K, int lda, int ldb, int ldc, float alpha)
{
    constexpr int BN = NBT * 32;

    const int tid  = threadIdx.x;
    const int lane = tid & 63;
    const int wave = tid >> 6;
    const int wr = wave >> 1, wc = wave & 1;
    const int l15 = lane & 15, lhi = lane >> 4;

    // XCD-aware bijective swizzle over the flattened grid (nwg % 8 == 0)
    const int GX = gridDim.x, GXY = gridDim.x * gridDim.y;
    const int nwg = GXY * gridDim.z;
    int lin = blockIdx.z * GXY + blockIdx.y * GX + blockIdx.x;
    int logical = (lin & 7) * (nwg >> 3) + (lin >> 3);
    const int bz = logical / GXY;
    int rem = logical - bz * GXY;
    const int bm = rem / GX;
    const int bn = rem - bm * GX;

    A  += (size_t)bz * sA;
    B  += (size_t)bz * sB;
    Co += (size_t)bz * sC;

    __shared__ f16 ldsA[128 * 64];
    __shared__ f16 ldsB[BN * 64];

    f32x4 acc[4][NBT] = {};

    // staging source column (elements), inverse-swizzled; constant per lane
    const int srcColE = ((lane & 7) ^ (lane >> 3)) * 8;
    const int rowBase = wave * 8 + (lane >> 3);          // + it*32
    const f16* Ag = A + (size_t)(bm * 128 + rowBase) * lda + srcColE;
    const f16* Bg = B + (size_t)(bn * BN  + rowBase) * ldb + srcColE;

    for (int k0 = 0; k0 < K; k0 += 64) {
#pragma unroll
        for (int it = 0; it < 4; ++it)
            gload_lds16(Ag + (size_t)(it * 32) * lda + k0,
                        (f16*)((char*)ldsA + it * 4096 + wave * 1024));
#pragma unroll
        for (int it = 0; it < NBT; ++it)
            gload_lds16(Bg + (size_t)(it * 32) * ldb + k0,
                        (f16*)((char*)ldsB + it * 4096 + wave * 1024));
        __syncthreads();
#pragma unroll
        for (int kk = 0; kk < 64; kk += 32) {
            const int kb2 = (kk + lhi * 8) * 2;   // byte col of fragment
            f16x8 af[4], bfr[NBT];
#pragma unroll
            for (int m = 0; m < 4; ++m) {
                int row = wr * 64 + m * 16 + l15;
                int phys = ((row * 128 + kb2) ^ ((row & 7) << 4)) >> 1;
                af[m] = *(const f16x8*)(ldsA + phys);
            }
#pragma unroll
            for (int n = 0; n < NBT; ++n) {
                int row = wc * (NBT * 16) + n * 16 + l15;
                int phys = ((row * 128 + kb2) ^ ((row & 7) << 4)) >> 1;
                bfr[n] = *(const f16x8*)(ldsB + phys);
            }
#pragma unroll
            for (int m = 0; m < 4; ++m)
#pragma unroll
                for (int n = 0; n < NBT; ++n)
                    acc[m][n] = __builtin_amdgcn_mfma_f32_16x16x32_f16(
                        af[m], bfr[n], acc[m][n], 0, 0, 0);
        }
        __syncthreads();
    }

    if constexpr (SOFTEXP) {
        // exp epilogue + deterministic per-block row sums (no atomics)
        __shared__ float rs2[2][128];
        float rowacc[16];
#pragma unroll
        for (int i = 0; i < 16; ++i) rowacc[i] = 0.f;
#pragma unroll
        for (int m = 0; m < 4; ++m) {
#pragma unroll
            for (int n = 0; n < NBT; ++n) {
                int col = bn * BN + wc * (NBT * 16) + n * 16 + l15;
#pragma unroll
                for (int r = 0; r < 4; ++r) {
                    int row = bm * 128 + wr * 64 + m * 16 + lhi * 4 + r;
                    float e = __expf(fminf(acc[m][n][r] * alpha, 11.0f));
                    rowacc[m * 4 + r] += e;
                    Co[(size_t)row * ldc + col] = (OUT_T)e;
                }
            }
        }
        // butterfly over l15 group (lanes sharing lhi hold the same rows)
#pragma unroll
        for (int off = 1; off < 16; off <<= 1)
#pragma unroll
            for (int i = 0; i < 16; ++i)
                rowacc[i] += __shfl_xor(rowacc[i], off);
        if (l15 == 0) {
#pragma unroll
            for (int i = 0; i < 16; ++i)
                rs2[wc][wr * 64 + (i >> 2) * 16 + lhi * 4 + (i & 3)] = rowacc[i];
        }
        __syncthreads();
        if (tid < 128) {
            int row = bm * 128 + tid;
            rowpart[((size_t)bz * M + row) * gridDim.x + bn] =
                rs2[0][tid] + rs2[1][tid];
        }
    } else {
#pragma unroll
        for (int m = 0; m < 4; ++m) {
#pragma unroll
            for (int n = 0; n < NBT; ++n) {
                int col = bn * BN + wc * (NBT * 16) + n * 16 + l15;
#pragma unroll
                for (int r = 0; r < 4; ++r) {
                    int row = bm * 128 + wr * 64 + m * 16 + lhi * 4 + r;
                    float v = acc[m][n][r] * alpha;
                    if (BIAS_MODE == 1) v += bias[row];
                    if (BIAS_MODE == 2) v += bias[col];
                    if (ROWSCALE) v *= rsinv[(size_t)bz * M + row];
                    if (RESID) v += resid[(size_t)bz * sR + (size_t)row * ldc + col];
                    Co[(size_t)row * ldc + col] = (OUT_T)v;
                }
            }
        }
    }
}

// ---------------------------------------------------------------------------
// rsinv[b*L + i] = 1 / sum_bn rowpart[(b*L+i)*nbn + bn]
// ---------------------------------------------------------------------------
__global__ __launch_bounds__(256) void rowsum_inv(
    const float* __restrict__ rowpart, float* __restrict__ rsinv, int nbn)
{
    int i = blockIdx.x * 256 + threadIdx.x;
    if (i < BB * LL) {
        float s = 0.f;
        for (int k = 0; k < nbn; ++k) s += rowpart[(size_t)i * nbn + k];
        rsinv[i] = 1.0f / s;
    }
}

// Fallback marker if workspace is too small (distinct absmax signal ~12345)
__global__ void fill_marker(float* out, int n)
{
    int i = blockIdx.x * 256 + threadIdx.x;
    if (i < n) out[i] = 12345.0f;
}

// ---------------------------------------------------------------------------
extern "C" void kernel_launch(void* const* d_in, const int* in_sizes, int n_in,
                              void* d_out, int out_size, void* d_ws, size_t ws_size,
                              hipStream_t stream)
{
    const float* x  = (const float*)d_in[0];
    const float* gw = (const float*)d_in[1];
    const float* gb = (const float*)d_in[2];
    const float* qw = (const float*)d_in[3];
    const float* qb = (const float*)d_in[4];
    const float* kw = (const float*)d_in[5];
    const float* kb = (const float*)d_in[6];
    const float* vw = (const float*)d_in[7];
    const float* vb = (const float*)d_in[8];
    const float* pw = (const float*)d_in[9];
    const float* pb = (const float*)d_in[10];
    float* out = (float*)d_out;

    // workspace layout (bytes)
    char* w = (char*)d_ws;
    float2* part  = (float2*)w;                       //   8 KB
    float2* stats = (float2*)(w + 8192);              //   256 B
    f16* Wqk  = (f16*)(w + 16384);                    //   1 MB   [1024,512]
    f16* Wv   = Wqk + (size_t)1024 * CC;              // 512 KB   [512,512]
    f16* Wp   = Wv  + (size_t)CC * CC;                // 512 KB
    float* qkb = (float*)(Wp + (size_t)CC * CC);      //   4 KB
    f16* xnT  = (f16*)((char*)qkb + 4096);            // 16 MB    [B][L,C]
    f16* QK   = xnT + (size_t)BB * LL * CC;           // 32 MB    [B][L,1024]
    f16* Vm   = QK  + (size_t)BB * LL * 1024;         // 16 MB    [B][C,L]
    f16* Pm   = Vm  + (size_t)BB * CC * LL;           // 64 MB    [B][L,L]
    float* rowpart = (float*)(Pm + (size_t)BB * LL * LL);  // 512 KB [B*L][8]
    float* rsinv   = rowpart + (size_t)BB * LL * 8;        // 64 KB  [B*L]
    f16* O2   = xnT;  // alias: xnT dead after gemm2  //          [B][L,C]
    size_t need = (size_t)((char*)(rsinv + (size_t)BB * LL) - w);
    if (ws_size < need) {
        fill_marker<<<(out_size + 255) / 256, 256, 0, stream>>>(out, out_size);
        return;
    }

    convert_w<<<dim3((CC * CC + 255) / 256), 256, 0, stream>>>(
        qw, kw, vw, pw, qb, kb, Wqk, Wv, Wp, qkb);
    gn_partial<<<dim3(32, GG, BB), 256, 0, stream>>>(x, part);
    gn_finalize<<<1, 64, 0, stream>>>(part, stats);
    gn_norm_t<<<dim3(LL / 64, CC / 64, BB), 256, 0, stream>>>(x, stats, gw, gb, xnT);

    // GEMM1: [Q|K]t[l, n] = xnT[l,:] . Wqk[n,:] + qkb[n]     (M=L, N=1024, K=C)
    gemm_bt<8, 2, false, false, false, f16><<<dim3(1024 / 256, LL / 128, BB), 256, 0, stream>>>(
        xnT, (size_t)LL * CC, Wqk, 0, QK, (size_t)LL * 1024, nullptr, 0, qkb,
        nullptr, nullptr,
        LL, 1024, CC, CC, CC, 1024, 1.0f);

    // GEMM2: V[c, l] = Wv[c,:] . xnT[l,:] + vb[c]            (M=C, N=L, K=C)
    gemm_bt<4, 1, false, false, false, f16><<<dim3(LL / 128, CC / 128, BB), 256, 0, stream>>>(
        Wv, 0, xnT, (size_t)LL * CC, Vm, (size_t)CC * LL, nullptr, 0, vb,
        nullptr, nullptr,
        CC, LL, CC, CC, CC, LL, 1.0f);

    // GEMM3: P'[i, j] = exp(scale * Qt[i,:] . Kt[j,:]) ; rowpart  (M=L, N=L, K=C)
    gemm_bt<8, 0, false, true, false, f16><<<dim3(LL / 256, LL / 128, BB), 256, 0, stream>>>(
        QK, (size_t)LL * 1024, QK + CC, (size_t)LL * 1024, Pm, (size_t)LL * LL,
        nullptr, 0, nullptr,
        rowpart, nullptr,
        LL, LL, CC, 1024, 1024, LL, 0.04419417382415922f);

    rowsum_inv<<<dim3((BB * LL + 255) / 256), 256, 0, stream>>>(rowpart, rsinv, LL / 256);

    // GEMM4: O2[i, c] = (P'[i,:] . V[c,:]) * rsinv[i]        (M=L, N=C, K=L)
    gemm_bt<4, 0, false, false, true, f16><<<dim3(CC / 128, LL / 128, BB), 256, 0, stream>>>(
        Pm, (size_t)LL * LL, Vm, (size_t)CC * LL, O2, (size_t)LL * CC,
        nullptr, 0, nullptr,
        nullptr, rsinv,
        LL, CC, LL, LL, LL, CC, 1.0f);

    // GEMM5: out[c, l] = Wp[c,:] . O2[l,:] + pb[c] + x[c,l]  (M=C, N=L, K=C)
    gemm_bt<4, 1, true, false, false, float><<<dim3(LL / 128, CC / 128, BB), 256, 0, stream>>>(
        Wp, 0, O2, (size_t)LL * CC, out, (size_t)CC * LL, x, (size_t)CC * LL, pb,
        nullptr, nullptr,
        CC, LL, CC, CC, CC, LL, 1.0f);
}

// Round 9
// 155.296 us; speedup vs baseline: 1.4532x; 1.0448x over previous
//
#include <hip/hip_runtime.h>

#define BB 8
#define CC 512
#define LL 2048
#define GG 4
#define CPG 128   // channels per group

typedef _Float16 f16;
typedef _Float16 f16x8 __attribute__((ext_vector_type(8)));
typedef float f32x4 __attribute__((ext_vector_type(4)));

__device__ __forceinline__ void gload_lds16(const f16* g, f16* l)
{
    __builtin_amdgcn_global_load_lds(
        (__attribute__((address_space(1))) void*)g,
        (__attribute__((address_space(3))) void*)l, 16, 0, 0);
}

// ---------------------------------------------------------------------------
// Fused: weight conversion (blocks 0-1023) + GroupNorm partial sums (1024-2047)
// ---------------------------------------------------------------------------
__global__ __launch_bounds__(256) void convert_gn(
    const float* __restrict__ qw, const float* __restrict__ kw,
    const float* __restrict__ vw, const float* __restrict__ pw,
    const float* __restrict__ qb, const float* __restrict__ kb,
    const float* __restrict__ x,
    f16* __restrict__ Wqk, f16* __restrict__ Wv, f16* __restrict__ Wp,
    float* __restrict__ qkb, float2* __restrict__ part)
{
    int bid = blockIdx.x;
    if (bid < 1024) {
        int i = bid * 256 + threadIdx.x;
        if (i < CC * CC) {
            Wqk[i]           = (f16)qw[i];
            Wqk[CC * CC + i] = (f16)kw[i];
            Wv[i]            = (f16)vw[i];
            Wp[i]            = (f16)pw[i];
        }
        if (i < CC) { qkb[i] = qb[i]; qkb[CC + i] = kb[i]; }
    } else {
        int r = bid - 1024;
        int s = r & 31, g = (r >> 5) & 3, b = r >> 7;
        const float4* p = (const float4*)(x + (size_t)b * CC * LL
                                            + (size_t)g * CPG * LL + (size_t)s * 8192);
        float sum = 0.f, sq = 0.f;
        for (int i = threadIdx.x; i < 2048; i += 256) {
            float4 v = p[i];
            sum += v.x + v.y + v.z + v.w;
            sq  += v.x * v.x + v.y * v.y + v.z * v.z + v.w * v.w;
        }
        for (int o = 32; o; o >>= 1) { sum += __shfl_xor(sum, o); sq += __shfl_xor(sq, o); }
        __shared__ float2 red[4];
        int wave = threadIdx.x >> 6, lane = threadIdx.x & 63;
        if (lane == 0) red[wave] = make_float2(sum, sq);
        __syncthreads();
        if (threadIdx.x == 0) {
            float S = red[0].x + red[1].x + red[2].x + red[3].x;
            float Q = red[0].y + red[1].y + red[2].y + red[3].y;
            part[((size_t)b * GG + g) * 32 + s] = make_float2(S, Q);
        }
    }
}

// GroupNorm normalize + affine + TRANSPOSE: x [C,L] fp32 -> xnT [L,C] f16.
// Stats derived in-block from the 32 per-slice partials (gn_finalize folded in).
__global__ __launch_bounds__(256) void gn_norm_t(
    const float* __restrict__ x, const float2* __restrict__ part,
    const float* __restrict__ gw, const float* __restrict__ gb,
    f16* __restrict__ xnT)
{
    __shared__ float t[64][65];
    __shared__ float2 stLds;
    int l0 = blockIdx.x * 64, c0 = blockIdx.y * 64, b = blockIdx.z;
    int tid = threadIdx.x;
    if (tid < 32) {
        float2 p = part[((size_t)b * GG + (c0 >> 7)) * 32 + tid];
        float s = p.x, q = p.y;
        for (int o = 16; o; o >>= 1) { s += __shfl_xor(s, o); q += __shfl_xor(q, o); }
        if (tid == 0) {
            const float invN = 1.0f / (float)(CPG * LL);
            float mean = s * invN;
            float var  = q * invN - mean * mean;
            stLds = make_float2(mean, rsqrtf(var + 1e-6f));
        }
    }
    __syncthreads();
    float2 st = stLds;
    const float* xb = x + (size_t)b * CC * LL;
    for (int i = tid; i < 4096; i += 256) {
        int c = i >> 6, l = i & 63;
        float v = xb[(size_t)(c0 + c) * LL + l0 + l];
        t[c][l] = (v - st.x) * st.y * gw[c0 + c] + gb[c0 + c];
    }
    __syncthreads();
    f16* o = xnT + (size_t)b * LL * CC;
    for (int i = tid; i < 4096; i += 256) {
        int l = i >> 6, c = i & 63;
        o[(size_t)(l0 + l) * CC + c0 + c] = (f16)t[c][l];
    }
}

// ---------------------------------------------------------------------------
// Batched GEMM  C[M,N] = alpha * A[M,K] · B[N,K]^T (+bias)(+resid)
// Tile 128 x (NBT*32), BK=64, 4 waves (2x2), per-wave 64 x (NBT*16).
//   NBT=4: 128x128 (proven R2 core, 32KB LDS), NBT=8: 128x256 (48KB LDS).
// Staging: global_load_lds w=16, linear LDS dest + inverse-swizzled source.
// Read swizzle: phys=(row*128+col)^((row&7)<<4), measured 0-conflict.
// XCD-aware bijective block swizzle (T1): logical = (hw&7)*(nwg/8) + hw>>3.
// Epilogue modes: BIAS_MODE 0/1(row)/2(col); RESID; SOFTEXP (exp + per-block
// row sums -> rowpart[(bz*M+row)*gridDim.x + bn]); ROWSCALE (reads the 8
// rowparts per row in a prologue, v *= 1/sum -- rowsum_inv folded in).
// ---------------------------------------------------------------------------
template<int NBT, int BIAS_MODE, bool RESID, bool SOFTEXP, bool ROWSCALE, typename OUT_T>
__global__ __launch_bounds__(256, 2) void gemm_bt(
    const f16* __restrict__ A, size_t sA,
    const f16* __restrict__ B, size_t sB,
    OUT_T* __restrict__ Co, size_t sC,
    const float* __restrict__ resid, size_t sR,
    const float* __restrict__ bias,
    float* __restrict__ rowpart,
    int M, int N, int K, int lda, int ldb, int ldc, float alpha)
{
    constexpr int BN = NBT * 32;

    const int tid  = threadIdx.x;
    const int lane = tid & 63;
    const int wave = tid >> 6;
    const int wr = wave >> 1, wc = wave & 1;
    const int l15 = lane & 15, lhi = lane >> 4;

    // XCD-aware bijective swizzle over the flattened grid (nwg % 8 == 0)
    const int GX = gridDim.x, GXY = gridDim.x * gridDim.y;
    const int nwg = GXY * gridDim.z;
    int lin = blockIdx.z * GXY + blockIdx.y * GX + blockIdx.x;
    int logical = (lin & 7) * (nwg >> 3) + (lin >> 3);
    const int bz = logical / GXY;
    int rem = logical - bz * GXY;
    const int bm = rem / GX;
    const int bn = rem - bm * GX;

    A  += (size_t)bz * sA;
    B  += (size_t)bz * sB;
    Co += (size_t)bz * sC;

    __shared__ f16 ldsA[128 * 64];
    __shared__ f16 ldsB[BN * 64];
    __shared__ float rsl[128];

    f32x4 acc[4][NBT] = {};

    if constexpr (ROWSCALE) {
        if (tid < 128) {
            const float* rp = rowpart + ((size_t)bz * M + bm * 128 + tid) * 8;
            float s = 0.f;
#pragma unroll
            for (int k = 0; k < 8; ++k) s += rp[k];
            rsl[tid] = 1.0f / s;
        }
        // first __syncthreads inside the K-loop orders rsl before epilogue use
    }

    // staging source column (elements), inverse-swizzled; constant per lane
    const int srcColE = ((lane & 7) ^ (lane >> 3)) * 8;
    const int rowBase = wave * 8 + (lane >> 3);          // + it*32
    const f16* Ag = A + (size_t)(bm * 128 + rowBase) * lda + srcColE;
    const f16* Bg = B + (size_t)(bn * BN  + rowBase) * ldb + srcColE;

    for (int k0 = 0; k0 < K; k0 += 64) {
#pragma unroll
        for (int it = 0; it < 4; ++it)
            gload_lds16(Ag + (size_t)(it * 32) * lda + k0,
                        (f16*)((char*)ldsA + it * 4096 + wave * 1024));
#pragma unroll
        for (int it = 0; it < NBT; ++it)
            gload_lds16(Bg + (size_t)(it * 32) * ldb + k0,
                        (f16*)((char*)ldsB + it * 4096 + wave * 1024));
        __syncthreads();
#pragma unroll
        for (int kk = 0; kk < 64; kk += 32) {
            const int kb2 = (kk + lhi * 8) * 2;   // byte col of fragment
            f16x8 af[4], bfr[NBT];
#pragma unroll
            for (int m = 0; m < 4; ++m) {
                int row = wr * 64 + m * 16 + l15;
                int phys = ((row * 128 + kb2) ^ ((row & 7) << 4)) >> 1;
                af[m] = *(const f16x8*)(ldsA + phys);
            }
#pragma unroll
            for (int n = 0; n < NBT; ++n) {
                int row = wc * (NBT * 16) + n * 16 + l15;
                int phys = ((row * 128 + kb2) ^ ((row & 7) << 4)) >> 1;
                bfr[n] = *(const f16x8*)(ldsB + phys);
            }
#pragma unroll
            for (int m = 0; m < 4; ++m)
#pragma unroll
                for (int n = 0; n < NBT; ++n)
                    acc[m][n] = __builtin_amdgcn_mfma_f32_16x16x32_f16(
                        af[m], bfr[n], acc[m][n], 0, 0, 0);
        }
        __syncthreads();
    }

    if constexpr (SOFTEXP) {
        // exp epilogue + deterministic per-block row sums (no atomics)
        __shared__ float rs2[2][128];
        float rowacc[16];
#pragma unroll
        for (int i = 0; i < 16; ++i) rowacc[i] = 0.f;
#pragma unroll
        for (int m = 0; m < 4; ++m) {
#pragma unroll
            for (int n = 0; n < NBT; ++n) {
                int col = bn * BN + wc * (NBT * 16) + n * 16 + l15;
#pragma unroll
                for (int r = 0; r < 4; ++r) {
                    int row = bm * 128 + wr * 64 + m * 16 + lhi * 4 + r;
                    float e = __expf(fminf(acc[m][n][r] * alpha, 11.0f));
                    rowacc[m * 4 + r] += e;
                    Co[(size_t)row * ldc + col] = (OUT_T)e;
                }
            }
        }
        // butterfly over l15 group (lanes sharing lhi hold the same rows)
#pragma unroll
        for (int off = 1; off < 16; off <<= 1)
#pragma unroll
            for (int i = 0; i < 16; ++i)
                rowacc[i] += __shfl_xor(rowacc[i], off);
        if (l15 == 0) {
#pragma unroll
            for (int i = 0; i < 16; ++i)
                rs2[wc][wr * 64 + (i >> 2) * 16 + lhi * 4 + (i & 3)] = rowacc[i];
        }
        __syncthreads();
        if (tid < 128) {
            int row = bm * 128 + tid;
            rowpart[((size_t)bz * M + row) * gridDim.x + bn] =
                rs2[0][tid] + rs2[1][tid];
        }
    } else {
#pragma unroll
        for (int m = 0; m < 4; ++m) {
#pragma unroll
            for (int n = 0; n < NBT; ++n) {
                int col = bn * BN + wc * (NBT * 16) + n * 16 + l15;
#pragma unroll
                for (int r = 0; r < 4; ++r) {
                    int row = bm * 128 + wr * 64 + m * 16 + lhi * 4 + r;
                    float v = acc[m][n][r] * alpha;
                    if (BIAS_MODE == 1) v += bias[row];
                    if (BIAS_MODE == 2) v += bias[col];
                    if (ROWSCALE) v *= rsl[row - bm * 128];
                    if (RESID) v += resid[(size_t)bz * sR + (size_t)row * ldc + col];
                    Co[(size_t)row * ldc + col] = (OUT_T)v;
                }
            }
        }
    }
}

// Fallback marker if workspace is too small (distinct absmax signal ~12345)
__global__ void fill_marker(float* out, int n)
{
    int i = blockIdx.x * 256 + threadIdx.x;
    if (i < n) out[i] = 12345.0f;
}

// ---------------------------------------------------------------------------
extern "C" void kernel_launch(void* const* d_in, const int* in_sizes, int n_in,
                              void* d_out, int out_size, void* d_ws, size_t ws_size,
                              hipStream_t stream)
{
    const float* x  = (const float*)d_in[0];
    const float* gw = (const float*)d_in[1];
    const float* gb = (const float*)d_in[2];
    const float* qw = (const float*)d_in[3];
    const float* qb = (const float*)d_in[4];
    const float* kw = (const float*)d_in[5];
    const float* kb = (const float*)d_in[6];
    const float* vw = (const float*)d_in[7];
    const float* vb = (const float*)d_in[8];
    const float* pw = (const float*)d_in[9];
    const float* pb = (const float*)d_in[10];
    float* out = (float*)d_out;

    // workspace layout (bytes)
    char* w = (char*)d_ws;
    float2* part  = (float2*)w;                       //   8 KB
    f16* Wqk  = (f16*)(w + 16384);                    //   1 MB   [1024,512]
    f16* Wv   = Wqk + (size_t)1024 * CC;              // 512 KB   [512,512]
    f16* Wp   = Wv  + (size_t)CC * CC;                // 512 KB
    float* qkb = (float*)(Wp + (size_t)CC * CC);      //   4 KB
    f16* xnT  = (f16*)((char*)qkb + 4096);            // 16 MB    [B][L,C]
    f16* QK   = xnT + (size_t)BB * LL * CC;           // 32 MB    [B][L,1024]
    f16* Vm   = QK  + (size_t)BB * LL * 1024;         // 16 MB    [B][C,L]
    f16* Pm   = Vm  + (size_t)BB * CC * LL;           // 64 MB    [B][L,L]
    float* rowpart = (float*)(Pm + (size_t)BB * LL * LL);  // 512 KB [B*L][8]
    f16* O2   = xnT;  // alias: xnT dead after gemm2  //          [B][L,C]
    size_t need = (size_t)((char*)(rowpart + (size_t)BB * LL * 8) - w);
    if (ws_size < need) {
        fill_marker<<<(out_size + 255) / 256, 256, 0, stream>>>(out, out_size);
        return;
    }

    convert_gn<<<dim3(2048), 256, 0, stream>>>(
        qw, kw, vw, pw, qb, kb, x, Wqk, Wv, Wp, qkb, part);
    gn_norm_t<<<dim3(LL / 64, CC / 64, BB), 256, 0, stream>>>(x, part, gw, gb, xnT);

    // GEMM1: [Q|K]t[l, n] = xnT[l,:] . Wqk[n,:] + qkb[n]     (M=L, N=1024, K=C)
    gemm_bt<8, 2, false, false, false, f16><<<dim3(1024 / 256, LL / 128, BB), 256, 0, stream>>>(
        xnT, (size_t)LL * CC, Wqk, 0, QK, (size_t)LL * 1024, nullptr, 0, qkb,
        nullptr,
        LL, 1024, CC, CC, CC, 1024, 1.0f);

    // GEMM2: V[c, l] = Wv[c,:] . xnT[l,:] + vb[c]            (M=C, N=L, K=C)
    gemm_bt<4, 1, false, false, false, f16><<<dim3(LL / 128, CC / 128, BB), 256, 0, stream>>>(
        Wv, 0, xnT, (size_t)LL * CC, Vm, (size_t)CC * LL, nullptr, 0, vb,
        nullptr,
        CC, LL, CC, CC, CC, LL, 1.0f);

    // GEMM3: P'[i, j] = exp(scale * Qt[i,:] . Kt[j,:]) ; rowpart  (M=L, N=L, K=C)
    gemm_bt<8, 0, false, true, false, f16><<<dim3(LL / 256, LL / 128, BB), 256, 0, stream>>>(
        QK, (size_t)LL * 1024, QK + CC, (size_t)LL * 1024, Pm, (size_t)LL * LL,
        nullptr, 0, nullptr,
        rowpart,
        LL, LL, CC, 1024, 1024, LL, 0.04419417382415922f);

    // GEMM4: O2[i, c] = (P'[i,:] . V[c,:]) / rowsum[i]       (M=L, N=C, K=L)
    gemm_bt<4, 0, false, false, true, f16><<<dim3(CC / 128, LL / 128, BB), 256, 0, stream>>>(
        Pm, (size_t)LL * LL, Vm, (size_t)CC * LL, O2, (size_t)LL * CC,
        nullptr, 0, nullptr,
        rowpart,
        LL, CC, LL, LL, LL, CC, 1.0f);

    // GEMM5: out[c, l] = Wp[c,:] . O2[l,:] + pb[c] + x[c,l]  (M=C, N=L, K=C)
    gemm_bt<4, 1, true, false, false, float><<<dim3(LL / 128, CC / 128, BB), 256, 0, stream>>>(
        Wp, 0, O2, (size_t)LL * CC, out, (size_t)CC * LL, x, (size_t)CC * LL, pb,
        nullptr,
        CC, LL, CC, CC, CC, LL, 1.0f);
}